// Round 18
// baseline (188.477 us; speedup 1.0000x reference)
//
#include <hip/hip_runtime.h>

// SNN with "swapped outputs" bug: stored state = spike (binary), forwarded
// value = membrane. reset = (spk_prev > 1) == 0 always -> mem = cur + 0.9*spk_prev.
// Constant input -> spike patterns fixate: mem0 const t>=1, mem1 t>=2, out t>=3.
// GEMM0 (256x2048,K=1024); GEMM1 {mem0(0),mem0(inf)} (M=512,K=2048);
// GEMM2 {mem1(0),mem1(1),mem1(inf)} (M=768,N=1024,K=2048); broadcast t>=3.
// Split-bf16 [h|l]: Ah.Wh + Ah.Wl + Al.Wh as one logical K'=3K GEMM; err ~1e-5.
// f64 fixup of elements within SDELTA=1e-3 of decision points -> exact decisions.
//
// Round-16 (185us): LDS XOR swizzle confirmed (+16.7us). Round 18 (= round-17
// retry; r17 was a compile error: __builtin_nontemporal_store needs a native
// clang vector, not HIP float4): split-K S=12 -> S=6 (halves the 226MB partial
// traffic; Kc=K/2 seg-aligned; grids 192/384/288 keep XCD swizzle bijective)
// + nontemporal stores for the 105MB broadcast via f32x4 ext_vector cast.

typedef unsigned short ushort_t;
typedef __attribute__((ext_vector_type(8))) short bf16x8;
typedef __attribute__((ext_vector_type(4))) float f32x4;

#define SDELTA 1.0e-3f
#define LCAP 65536
#define NS 6   // split-K factor

__device__ inline ushort_t f2bf(float f) {       // RNE f32 -> bf16
    unsigned u = __float_as_uint(f);
    u += 0x7FFFu + ((u >> 16) & 1u);
    return (ushort_t)(u >> 16);
}
__device__ inline float bf2f(ushort_t h) { return __uint_as_float((unsigned)h << 16); }
__device__ inline float4 ld4(const float* p) { return *reinterpret_cast<const float4*>(p); }

__device__ inline void gload16(const void* g, void* l) {
    __builtin_amdgcn_global_load_lds(
        (__attribute__((address_space(1))) void*)g,
        (__attribute__((address_space(3))) void*)l, 16, 0, 0);
}

// ---- 128x128 split-K GEMM over logical K'=3K, physical [h|l] storage ----
// 1D grid nwg = nx*ny*NS (nwg%8==0); XCD-chunked swizzle; Kc=K/2 seg-aligned.
// LDS: linear dest (gload_lds), XOR-swizzled global source column, XOR reads.
__global__ __launch_bounds__(256) void gemm_splitk(
    const ushort_t* __restrict__ A,   // [M, 2K] bf16: [Ah|Al]
    const ushort_t* __restrict__ W,   // [N, 2K] bf16: [Wh|Wl]
    float* __restrict__ P,            // [S, M, N] f32 partials
    int M, int N, int K, int Kc, int nx, int ny)
{
    __shared__ ushort_t As[128 * 64];
    __shared__ ushort_t Ws[128 * 64];

    const int nwg = gridDim.x;
    const int lin = blockIdx.x;
    const int swzb = (lin & 7) * (nwg >> 3) + (lin >> 3);
    const int nxy = nx * ny;
    const int bz  = swzb / nxy;
    const int rem = swzb - bz * nxy;
    const int by  = rem / nx;
    const int bx  = rem - by * nx;

    const int tid  = threadIdx.x;
    const int lane = tid & 63;
    const int wid  = tid >> 6;
    const int row0 = by * 128;
    const int col0 = bx * 128;
    const int k0   = bz * Kc;          // logical k in [0, 3K)
    const int st   = 2 * K;            // physical row stride
    const int aoff = (k0 < K) ? k0 : (k0 - K);           // A logical [h,h,l]
    const int woff = (k0 < 2 * K) ? k0 : (k0 - 2 * K);   // W logical [h,l,h]

    // staging: lane (r = lane>>3, c = lane&7) loads global chunk c ^ (r&7);
    // LDS dest linear -> LDS[row][chunk c] = global[row][chunk c^(row&7)]
    const int srow = wid * 32 + (lane >> 3);
    const int scol = (((lane & 7) ^ ((lane >> 3) & 7))) * 8;
    const ushort_t* Ag = A + (size_t)(row0 + srow) * st + aoff + scol;
    const ushort_t* Wg = W + (size_t)(col0 + srow) * st + woff + scol;

    const int wr = wid >> 1, wc = wid & 1;
    const int l15 = lane & 15;
    const int kh  = lane >> 4;
    const int swz8 = l15 & 7;
    const int ch0 = ((kh + 0) ^ swz8) * 8;   // ks=0: global chunk kh, swizzled
    const int ch1 = ((kh + 4) ^ swz8) * 8;   // ks=1: global chunk kh+4
    int aRow[4], bRow[4];
#pragma unroll
    for (int m = 0; m < 4; ++m) aRow[m] = (wr * 64 + m * 16 + l15) * 64;
#pragma unroll
    for (int n = 0; n < 4; ++n) bRow[n] = (wc * 64 + n * 16 + l15) * 64;

    f32x4 acc[4][4] = {};
    const int NIT = Kc / 64;

    for (int it = 0; it < NIT; ++it) {
        const int kk = it * 64;
#pragma unroll
        for (int i = 0; i < 4; ++i) {
            gload16(Ag + (size_t)(i * 8) * st + kk, &As[(wid * 32 + i * 8) * 64]);
            gload16(Wg + (size_t)(i * 8) * st + kk, &Ws[(wid * 32 + i * 8) * 64]);
        }
        __syncthreads();
#pragma unroll
        for (int ks = 0; ks < 2; ++ks) {
            const int ch = ks ? ch1 : ch0;
            bf16x8 af[4], bf[4];
#pragma unroll
            for (int m = 0; m < 4; ++m)
                af[m] = *reinterpret_cast<const bf16x8*>(&As[aRow[m] + ch]);
#pragma unroll
            for (int n = 0; n < 4; ++n)
                bf[n] = *reinterpret_cast<const bf16x8*>(&Ws[bRow[n] + ch]);
#pragma unroll
            for (int m = 0; m < 4; ++m)
#pragma unroll
                for (int n = 0; n < 4; ++n)
                    acc[m][n] = __builtin_amdgcn_mfma_f32_16x16x32_bf16(
                        af[m], bf[n], acc[m][n], 0, 0, 0);
        }
        __syncthreads();
    }

    float* Pp = P + ((size_t)bz * M + row0) * N + col0;
#pragma unroll
    for (int n = 0; n < 4; ++n) {
        const int col = wc * 64 + n * 16 + l15;
#pragma unroll
        for (int m = 0; m < 4; ++m) {
            const int rb = wr * 64 + m * 16 + kh * 4;
#pragma unroll
            for (int i = 0; i < 4; ++i)
                Pp[(size_t)(rb + i) * N + col] = acc[m][n][i];
        }
    }
}

// ---------------- merged split-conversions ([h|l], width 2K) + ctr zero ----------------
__device__ inline void do_split(const float4* src, ushort_t* dst, int i, int logK)
{
    float4 v = src[i];
    const int K = 1 << logK;
    const int e0 = i * 4;
    const int r = e0 >> logK, k = e0 & (K - 1);
    ushort_t* row = dst + (size_t)r * 2 * K;
    ushort4 h, l;
    h.x = f2bf(v.x); l.x = f2bf(v.x - bf2f(h.x));
    h.y = f2bf(v.y); l.y = f2bf(v.y - bf2f(h.y));
    h.z = f2bf(v.z); l.z = f2bf(v.z - bf2f(h.z));
    h.w = f2bf(v.w); l.w = f2bf(v.w - bf2f(h.w));
    *reinterpret_cast<ushort4*>(row + k) = h;
    *reinterpret_cast<ushort4*>(row + K + k) = l;
}

__global__ __launch_bounds__(256) void cvt_all(
    const float4* __restrict__ x,  const float4* __restrict__ W0,
    const float4* __restrict__ W1, const float4* __restrict__ W2,
    ushort_t* __restrict__ xb,  ushort_t* __restrict__ Wb0,
    ushort_t* __restrict__ Wb1, ushort_t* __restrict__ Wb2,
    int* __restrict__ ctrs)
{
    const int b = blockIdx.x, tid = threadIdx.x;
    if (b == 0 && tid < 3) ctrs[tid * 16] = 0;
    if (b < 256)        do_split(x,  xb,  b * 256 + tid,          10);
    else if (b < 2304)  do_split(W0, Wb0, (b - 256) * 256 + tid,  10);
    else if (b < 6400)  do_split(W1, Wb1, (b - 2304) * 256 + tid, 11);
    else                do_split(W2, Wb2, (b - 6400) * 256 + tid, 11);
}

// ---------------- wave compaction of flagged indices ----------------
__device__ inline void emit(const int* loc, int lc, int* list, int* counter)
{
    const int lane = threadIdx.x & 63;
    int inc = lc;
#pragma unroll
    for (int off = 1; off < 64; off <<= 1) {
        int t = __shfl_up(inc, off);
        if (lane >= off) inc += t;
    }
    const int total = __shfl(inc, 63);
    int base = 0;
    if (lane == 63 && total) base = atomicAdd(counter, total);
    base = __shfl(base, 63);
    const int excl = inc - lc;
    for (int j = 0; j < lc; ++j) {
        int p = base + excl + j;
        if (p < LCAP) list[p] = loc[j];
    }
}

__device__ inline int flag4(float4 v, int e0, int* loc, int lc)
{
    float vv[4] = {v.x, v.y, v.z, v.w};
#pragma unroll
    for (int c = 0; c < 4; ++c)
        if ((fabsf(vv[c] - 1.0f) < SDELTA) || (fabsf(vv[c] - 0.1f) < SDELTA))
            loc[lc++] = e0 + c;
    return lc;
}

__device__ inline void wsplit2(ushort_t* row, int k, float4 v)   // [h|l], width 4096
{
    ushort4 h, l;
    h.x = f2bf(v.x); l.x = f2bf(v.x - bf2f(h.x));
    h.y = f2bf(v.y); l.y = f2bf(v.y - bf2f(h.y));
    h.z = f2bf(v.z); l.z = f2bf(v.z - bf2f(h.z));
    h.w = f2bf(v.w); l.w = f2bf(v.w - bf2f(h.w));
    *reinterpret_cast<ushort4*>(row + k) = h;
    *reinterpret_cast<ushort4*>(row + 2048 + k) = l;
}

__device__ inline void patch2(ushort_t* row, int c, float v)
{
    ushort_t h = f2bf(v);
    ushort_t l = f2bf(v - bf2f(h));
    row[c] = h; row[2048 + c] = l;
}

__device__ inline float4 lifstep(float4 cur, float4 gate)
{
    float4 o;
    o.x = cur.x + ((gate.x > 1.0f) ? 0.9f : 0.0f);
    o.y = cur.y + ((gate.y > 1.0f) ? 0.9f : 0.0f);
    o.z = cur.z + ((gate.z > 1.0f) ? 0.9f : 0.0f);
    o.w = cur.w + ((gate.w > 1.0f) ? 0.9f : 0.0f);
    return o;
}

__device__ inline double wred(double p)
{
#pragma unroll
    for (int off = 32; off; off >>= 1) p += __shfl_down(p, off);
    return __shfl(p, 0);
}

// ---- layer 0 epilogue: reduce S=NS + bias, scan, C0 write, A1 [h|l] ----
__global__ __launch_bounds__(256) void fused0(
    const float4* __restrict__ P, const float* __restrict__ bias,
    float4* __restrict__ C0, ushort_t* __restrict__ A1b,
    int* __restrict__ list, int* __restrict__ counter)
{
    const int i = blockIdx.x * 256 + threadIdx.x;   // < 131072
    float4 s = P[i];
#pragma unroll
    for (int j = 1; j < NS; ++j) {
        float4 t = P[(size_t)j * 131072 + i];
        s.x += t.x; s.y += t.y; s.z += t.z; s.w += t.w;
    }
    const float4 bv = *reinterpret_cast<const float4*>(bias + ((i * 4) & 2047));
    s.x += bv.x; s.y += bv.y; s.z += bv.z; s.w += bv.w;
    C0[i] = s;
    int loc[4];
    int lc = flag4(s, i * 4, loc, 0);
    emit(loc, lc, list, counter);
    float4 mi = lifstep(s, s);
    const int e0 = i * 4, r = e0 >> 11, k = e0 & 2047;
    wsplit2(A1b + (size_t)r * 4096, k, s);
    wsplit2(A1b + (size_t)(256 + r) * 4096, k, mi);
}

// ---- layer 1 epilogue: reduce S=NS both halves, scan, C1, A2 [h|l] ----
__global__ __launch_bounds__(256) void fused1(
    const float4* __restrict__ P, const float* __restrict__ bias,
    float4* __restrict__ C1, ushort_t* __restrict__ A2b,
    int* __restrict__ list, int* __restrict__ counter)
{
    const int i = blockIdx.x * 256 + threadIdx.x;   // < 131072
    float4 c0 = P[i];
    float4 ci = P[131072 + i];
#pragma unroll
    for (int j = 1; j < NS; ++j) {
        float4 t0 = P[(size_t)j * 262144 + i];
        float4 t1 = P[(size_t)j * 262144 + 131072 + i];
        c0.x += t0.x; c0.y += t0.y; c0.z += t0.z; c0.w += t0.w;
        ci.x += t1.x; ci.y += t1.y; ci.z += t1.z; ci.w += t1.w;
    }
    const float4 bv = *reinterpret_cast<const float4*>(bias + ((i * 4) & 2047));
    c0.x += bv.x; c0.y += bv.y; c0.z += bv.z; c0.w += bv.w;
    ci.x += bv.x; ci.y += bv.y; ci.z += bv.z; ci.w += bv.w;
    C1[i] = c0;
    C1[131072 + i] = ci;
    int loc[8];
    int lc = flag4(c0, i * 4, loc, 0);
    lc = flag4(ci, (131072 + i) * 4, loc, lc);
    emit(loc, lc, list, counter);
    float4 m1 = lifstep(ci, c0);
    float4 m2 = lifstep(ci, m1);
    const int e0 = i * 4, r = e0 >> 11, k = e0 & 2047;
    wsplit2(A2b + (size_t)r * 4096, k, c0);
    wsplit2(A2b + (size_t)(256 + r) * 4096, k, m1);
    wsplit2(A2b + (size_t)(512 + r) * 4096, k, m2);
}

// ---- layer 2 epilogue: reduce S=NS + bias + scan -> C2 ----
__global__ __launch_bounds__(256) void reduce_scan2(
    const float4* __restrict__ P, const float* __restrict__ bias,
    float4* __restrict__ C2, int* __restrict__ list, int* __restrict__ counter)
{
    const int i = blockIdx.x * 256 + threadIdx.x;   // < 196608
    float4 s = P[i];
#pragma unroll
    for (int j = 1; j < NS; ++j) {
        float4 t = P[(size_t)j * 196608 + i];
        s.x += t.x; s.y += t.y; s.z += t.z; s.w += t.w;
    }
    const float4 bv = *reinterpret_cast<const float4*>(bias + ((i * 4) & 1023));
    s.x += bv.x; s.y += bv.y; s.z += bv.z; s.w += bv.w;
    C2[i] = s;
    int loc[4];
    int lc = flag4(s, i * 4, loc, 0);
    emit(loc, lc, list, counter);
}

// ---------------- fixups: exact f64 dots, patch C and A [h|l] ----------------
__global__ __launch_bounds__(256) void fixup0(
    float* __restrict__ C0, ushort_t* __restrict__ A1b,
    const float* __restrict__ X, const float* __restrict__ W0,
    const float* __restrict__ b0,
    const int* __restrict__ list, const int* __restrict__ counter)
{
    const int lane = threadIdx.x & 63;
    const int wave = (blockIdx.x * 256 + threadIdx.x) >> 6;
    const int nw = gridDim.x * 4;
    const int nbad = min(*counter, LCAP);
    const int chunk = (nbad + nw - 1) / nw;
    for (int e = wave * chunk; e < min(wave * chunk + chunk, nbad); ++e) {
        const int idx = list[e];
        const int rr = idx >> 11, cc = idx & 2047;
        double p = 0.0;
        for (int k = lane * 4; k < 1024; k += 256) {
            float4 a4 = ld4(X + (size_t)rr * 1024 + k);
            float4 w4 = ld4(W0 + (size_t)cc * 1024 + k);
            p = fma((double)a4.x, (double)w4.x, p);
            p = fma((double)a4.y, (double)w4.y, p);
            p = fma((double)a4.z, (double)w4.z, p);
            p = fma((double)a4.w, (double)w4.w, p);
        }
        const double tot = wred(p);
        if (lane == 0) {
            float c = (float)(tot + (double)b0[cc]);
            C0[idx] = c;
            float mi = c + ((c > 1.0f) ? 0.9f : 0.0f);
            patch2(A1b + (size_t)rr * 4096, cc, c);
            patch2(A1b + (size_t)(256 + rr) * 4096, cc, mi);
        }
    }
}

__global__ __launch_bounds__(256) void fixup1(
    float* __restrict__ C1, ushort_t* __restrict__ A2b,
    const float* __restrict__ C0, const float* __restrict__ W1,
    const float* __restrict__ b1,
    const int* __restrict__ list, const int* __restrict__ counter)
{
    const int lane = threadIdx.x & 63;
    const int wave = (blockIdx.x * 256 + threadIdx.x) >> 6;
    const int nw = gridDim.x * 4;
    const int nbad = min(*counter, LCAP);
    const int chunk = (nbad + nw - 1) / nw;
    for (int e = wave * chunk; e < min(wave * chunk + chunk, nbad); ++e) {
        const int idx = list[e];
        const int rr = idx >> 11, cc = idx & 2047;
        const int rp = rr & 255;
        double p0 = 0.0, p1 = 0.0;
        for (int k = lane * 4; k < 2048; k += 256) {
            float4 a4 = ld4(C0 + (size_t)rp * 2048 + k);   // mem0(0) row
            float4 w4 = ld4(W1 + (size_t)cc * 2048 + k);
            float4 b4 = lifstep(a4, a4);                    // mem0(inf) row
            p0 = fma((double)a4.x, (double)w4.x, p0);
            p0 = fma((double)a4.y, (double)w4.y, p0);
            p0 = fma((double)a4.z, (double)w4.z, p0);
            p0 = fma((double)a4.w, (double)w4.w, p0);
            p1 = fma((double)b4.x, (double)w4.x, p1);
            p1 = fma((double)b4.y, (double)w4.y, p1);
            p1 = fma((double)b4.z, (double)w4.z, p1);
            p1 = fma((double)b4.w, (double)w4.w, p1);
        }
        const double t0 = wred(p0);
        const double t1 = wred(p1);
        if (lane == 0) {
            float c0 = (float)(t0 + (double)b1[cc]);
            float ci = (float)(t1 + (double)b1[cc]);
            C1[(size_t)rp * 2048 + cc] = c0;
            C1[(size_t)(256 + rp) * 2048 + cc] = ci;
            float m1 = ci + ((c0 > 1.0f) ? 0.9f : 0.0f);
            float m2 = ci + ((m1 > 1.0f) ? 0.9f : 0.0f);
            patch2(A2b + (size_t)rp * 4096, cc, c0);
            patch2(A2b + (size_t)(256 + rp) * 4096, cc, m1);
            patch2(A2b + (size_t)(512 + rp) * 4096, cc, m2);
        }
    }
}

__global__ __launch_bounds__(256) void fixup2(
    float* __restrict__ C2, const float* __restrict__ C1,
    const float* __restrict__ W2, const float* __restrict__ b2,
    const int* __restrict__ list, const int* __restrict__ counter)
{
    const int lane = threadIdx.x & 63;
    const int wave = (blockIdx.x * 256 + threadIdx.x) >> 6;
    const int nw = gridDim.x * 4;
    const int nbad = min(*counter, LCAP);
    const int chunk = (nbad + nw - 1) / nw;
    for (int e = wave * chunk; e < min(wave * chunk + chunk, nbad); ++e) {
        const int idx = list[e];
        const int rr = idx >> 10, cc = idx & 1023;
        const int rp = rr & 255;
        double pA = 0.0, pB = 0.0, pC = 0.0;
        for (int k = lane * 4; k < 2048; k += 256) {
            float4 c04 = ld4(C1 + (size_t)rp * 2048 + k);
            float4 ci4 = ld4(C1 + (size_t)(256 + rp) * 2048 + k);
            float4 w4  = ld4(W2 + (size_t)cc * 2048 + k);
            float4 m14 = lifstep(ci4, c04);
            float4 m24 = lifstep(ci4, m14);
            pA = fma((double)c04.x, (double)w4.x, pA);
            pA = fma((double)c04.y, (double)w4.y, pA);
            pA = fma((double)c04.z, (double)w4.z, pA);
            pA = fma((double)c04.w, (double)w4.w, pA);
            pB = fma((double)m14.x, (double)w4.x, pB);
            pB = fma((double)m14.y, (double)w4.y, pB);
            pB = fma((double)m14.z, (double)w4.z, pB);
            pB = fma((double)m14.w, (double)w4.w, pB);
            pC = fma((double)m24.x, (double)w4.x, pC);
            pC = fma((double)m24.y, (double)w4.y, pC);
            pC = fma((double)m24.z, (double)w4.z, pC);
            pC = fma((double)m24.w, (double)w4.w, pC);
        }
        const double tA = wred(pA);
        const double tB = wred(pB);
        const double tC = wred(pC);
        if (lane == 0) {
            C2[(size_t)rp * 1024 + cc]         = (float)(tA + (double)b2[cc]);
            C2[(size_t)(256 + rp) * 1024 + cc] = (float)(tB + (double)b2[cc]);
            C2[(size_t)(512 + rp) * 1024 + cc] = (float)(tC + (double)b2[cc]);
        }
    }
}

// Final layer + broadcast; grid.y covers 4 time-slices each; NT stores
// through native ext_vector f32x4 (HIP float4 is rejected by the builtin).
__global__ __launch_bounds__(256) void lif2_bcast(const float4* __restrict__ c2,
                                                  f32x4* __restrict__ out, int n4)
{
    int i = blockIdx.x * 256 + threadIdx.x;
    if (i >= n4) return;
    float4 c0 = c2[i], c1 = c2[n4 + i], ci = c2[2 * n4 + i];
    float4 m0 = c0;
    float4 m1 = lifstep(c1, m0);
    float4 m2 = lifstep(ci, m1);
    float4 m3 = lifstep(ci, m2);
    int t0 = blockIdx.y * 4;
#pragma unroll
    for (int j = 0; j < 4; ++j) {
        int t = t0 + j;
        float4 v = (t == 0) ? m0 : (t == 1) ? m1 : (t == 2) ? m2 : m3;
        f32x4 nv = {v.x, v.y, v.z, v.w};
        __builtin_nontemporal_store(nv, &out[(size_t)t * n4 + i]);
    }
}

extern "C" void kernel_launch(void* const* d_in, const int* in_sizes, int n_in,
                              void* d_out, int out_size, void* d_ws, size_t ws_size,
                              hipStream_t stream)
{
    const float* x  = (const float*)d_in[0];  // [256,1024]
    const float* W0 = (const float*)d_in[1];  // [2048,1024]
    const float* b0 = (const float*)d_in[2];
    const float* W1 = (const float*)d_in[3];  // [2048,2048]
    const float* b1 = (const float*)d_in[4];
    const float* W2 = (const float*)d_in[5];  // [1024,2048]
    const float* b2 = (const float*)d_in[6];
    float* out = (float*)d_out;
    float* ws  = (float*)d_ws;

    // ws (floats): C0 0.5M | C1 1M | C2 0.75M | ctrs | lists 3x64K
    float* C0 = ws;
    float* C1 = ws + 524288;
    float* C2 = ws + 1572864;
    int* ctrs  = (int*)(ws + 2359296);
    int* list0 = (int*)(ws + 2359360);
    int* list1 = (int*)(ws + 2424896);
    int* list2 = (int*)(ws + 2490432);

    // d_out scratch (ALL overwritten by lif2_bcast at the end), float offsets:
    ushort_t* Wb0 = (ushort_t*)(out);               // [2048,2048] bf16 = 2M floats
    ushort_t* Wb1 = (ushort_t*)(out + 2097152);     // [2048,4096] bf16 = 4M floats
    ushort_t* Wb2 = (ushort_t*)(out + 6291456);     // [1024,4096] bf16 = 2M floats
    ushort_t* xb  = (ushort_t*)(out + 8388608);     // [256,2048]  bf16 = 256K floats
    ushort_t* A1b = (ushort_t*)(out + 8650752);     // [512,4096]  bf16 = 1M floats
    ushort_t* A2b = (ushort_t*)(out + 9699328);     // [768,4096]  bf16 = 1.5M floats
    float* Pbuf   = out + 11272192;                 // partials, max 6.3M -> 17.6M < 26.2M

    dim3 blk(256);

    // 1: all split-conversions ([h|l]) + counter zeroing
    cvt_all<<<dim3(8448), blk, 0, stream>>>((const float4*)x, (const float4*)W0,
                                            (const float4*)W1, (const float4*)W2,
                                            xb, Wb0, Wb1, Wb2, ctrs);

    // 2-4: layer 0. K'=3072, Kc=512, S=6 -> 16x2x6 = 192 blocks
    gemm_splitk<<<dim3(192), blk, 0, stream>>>(xb, Wb0, Pbuf, 256, 2048, 1024, 512, 16, 2);
    fused0<<<dim3(512), blk, 0, stream>>>((const float4*)Pbuf, b0, (float4*)C0,
                                          A1b, list0, ctrs + 0);
    fixup0<<<dim3(256), blk, 0, stream>>>(C0, A1b, x, W0, b0, list0, ctrs + 0);

    // 5-7: layer 1. K'=6144, Kc=1024, S=6 -> 16x4x6 = 384 blocks
    gemm_splitk<<<dim3(384), blk, 0, stream>>>(A1b, Wb1, Pbuf, 512, 2048, 2048, 1024, 16, 4);
    fused1<<<dim3(512), blk, 0, stream>>>((const float4*)Pbuf, b1, (float4*)C1,
                                          A2b, list1, ctrs + 16);
    fixup1<<<dim3(256), blk, 0, stream>>>(C1, A2b, C0, W1, b1, list1, ctrs + 16);

    // 8-10: layer 2. K'=6144, Kc=1024, S=6 -> 8x6x6 = 288 blocks
    gemm_splitk<<<dim3(288), blk, 0, stream>>>(A2b, Wb2, Pbuf, 768, 1024, 2048, 1024, 8, 6);
    reduce_scan2<<<dim3(768), blk, 0, stream>>>((const float4*)Pbuf, b2, (float4*)C2,
                                                list2, ctrs + 32);
    fixup2<<<dim3(256), blk, 0, stream>>>(C2, C1, W2, b2, list2, ctrs + 32);

    // 11: layer-2 LIF chain + output broadcast (overwrites all of d_out)
    lif2_bcast<<<dim3(256, 25), blk, 0, stream>>>((const float4*)C2, (f32x4*)out, 65536);
}

// Round 19
// 181.606 us; speedup vs baseline: 1.0378x; 1.0378x over previous
//
#include <hip/hip_runtime.h>

// SNN with "swapped outputs" bug: stored state = spike (binary), forwarded
// value = membrane. reset = (spk_prev > 1) == 0 always -> mem = cur + 0.9*spk_prev.
// Constant input -> spike patterns fixate: mem0 const t>=1, mem1 t>=2, out t>=3.
// GEMM0 (256x2048,K=1024); GEMM1 {mem0(0),mem0(inf)} (M=512,K=2048);
// GEMM2 {mem1(0),mem1(1),mem1(inf)} (M=768,N=1024,K=2048); broadcast t>=3.
// Split-bf16 [h|l]: Ah.Wh + Ah.Wl + Al.Wh as one logical K'=3K GEMM; err ~1e-5.
// f64 fixup of elements within SDELTA=1e-3 of decision points -> exact decisions.
//
// Round-18 lesson: split-K partials are L3-resident; S=6 saved no HBM time and
// cost occupancy (+3.4us). Round 19 = round-16 config (S=12, best measured
// 185.1us) + heterogeneous-grid overlap: W1/W2 conversions (6144 blocks of
// pure BW work, not needed until GEMM1/2) are merged INTO the GEMM0 dispatch
// as extra blocks, running on the CUs GEMM0's 384 blocks leave idle.

typedef unsigned short ushort_t;
typedef __attribute__((ext_vector_type(8))) short bf16x8;
typedef __attribute__((ext_vector_type(4))) float f32x4;

#define SDELTA 1.0e-3f
#define LCAP 65536
#define NS 12   // split-K factor

__device__ inline ushort_t f2bf(float f) {       // RNE f32 -> bf16
    unsigned u = __float_as_uint(f);
    u += 0x7FFFu + ((u >> 16) & 1u);
    return (ushort_t)(u >> 16);
}
__device__ inline float bf2f(ushort_t h) { return __uint_as_float((unsigned)h << 16); }
__device__ inline float4 ld4(const float* p) { return *reinterpret_cast<const float4*>(p); }

__device__ inline void gload16(const void* g, void* l) {
    __builtin_amdgcn_global_load_lds(
        (__attribute__((address_space(1))) void*)g,
        (__attribute__((address_space(3))) void*)l, 16, 0, 0);
}

__device__ inline void do_split(const float4* src, ushort_t* dst, int i, int logK)
{
    float4 v = src[i];
    const int K = 1 << logK;
    const int e0 = i * 4;
    const int r = e0 >> logK, k = e0 & (K - 1);
    ushort_t* row = dst + (size_t)r * 2 * K;
    ushort4 h, l;
    h.x = f2bf(v.x); l.x = f2bf(v.x - bf2f(h.x));
    h.y = f2bf(v.y); l.y = f2bf(v.y - bf2f(h.y));
    h.z = f2bf(v.z); l.z = f2bf(v.z - bf2f(h.z));
    h.w = f2bf(v.w); l.w = f2bf(v.w - bf2f(h.w));
    *reinterpret_cast<ushort4*>(row + k) = h;
    *reinterpret_cast<ushort4*>(row + K + k) = l;
}

// ---- GEMM core: 128x128 split-K over logical K'=3K, physical [h|l] ----
// LDS: linear dest (gload_lds), XOR-swizzled global source column, XOR reads.
__device__ __attribute__((always_inline)) inline void gemm_body(
    const ushort_t* __restrict__ A, const ushort_t* __restrict__ W,
    float* __restrict__ P, int M, int N, int K, int Kc, int nx, int ny,
    int lin, int nwg, ushort_t* As, ushort_t* Ws)
{
    const int swzb = (lin & 7) * (nwg >> 3) + (lin >> 3);
    const int nxy = nx * ny;
    const int bz  = swzb / nxy;
    const int rem = swzb - bz * nxy;
    const int by  = rem / nx;
    const int bx  = rem - by * nx;

    const int tid  = threadIdx.x;
    const int lane = tid & 63;
    const int wid  = tid >> 6;
    const int row0 = by * 128;
    const int col0 = bx * 128;
    const int k0   = bz * Kc;          // logical k in [0, 3K)
    const int st   = 2 * K;            // physical row stride
    const int aoff = (k0 < K) ? k0 : (k0 - K);           // A logical [h,h,l]
    const int woff = (k0 < 2 * K) ? k0 : (k0 - 2 * K);   // W logical [h,l,h]

    const int srow = wid * 32 + (lane >> 3);
    const int scol = (((lane & 7) ^ ((lane >> 3) & 7))) * 8;
    const ushort_t* Ag = A + (size_t)(row0 + srow) * st + aoff + scol;
    const ushort_t* Wg = W + (size_t)(col0 + srow) * st + woff + scol;

    const int wr = wid >> 1, wc = wid & 1;
    const int l15 = lane & 15;
    const int kh  = lane >> 4;
    const int swz8 = l15 & 7;
    const int ch0 = ((kh + 0) ^ swz8) * 8;
    const int ch1 = ((kh + 4) ^ swz8) * 8;
    int aRow[4], bRow[4];
#pragma unroll
    for (int m = 0; m < 4; ++m) aRow[m] = (wr * 64 + m * 16 + l15) * 64;
#pragma unroll
    for (int n = 0; n < 4; ++n) bRow[n] = (wc * 64 + n * 16 + l15) * 64;

    f32x4 acc[4][4] = {};
    const int NIT = Kc / 64;

    for (int it = 0; it < NIT; ++it) {
        const int kk = it * 64;
#pragma unroll
        for (int i = 0; i < 4; ++i) {
            gload16(Ag + (size_t)(i * 8) * st + kk, &As[(wid * 32 + i * 8) * 64]);
            gload16(Wg + (size_t)(i * 8) * st + kk, &Ws[(wid * 32 + i * 8) * 64]);
        }
        __syncthreads();
#pragma unroll
        for (int ks = 0; ks < 2; ++ks) {
            const int ch = ks ? ch1 : ch0;
            bf16x8 af[4], bf[4];
#pragma unroll
            for (int m = 0; m < 4; ++m)
                af[m] = *reinterpret_cast<const bf16x8*>(&As[aRow[m] + ch]);
#pragma unroll
            for (int n = 0; n < 4; ++n)
                bf[n] = *reinterpret_cast<const bf16x8*>(&Ws[bRow[n] + ch]);
#pragma unroll
            for (int m = 0; m < 4; ++m)
#pragma unroll
                for (int n = 0; n < 4; ++n)
                    acc[m][n] = __builtin_amdgcn_mfma_f32_16x16x32_bf16(
                        af[m], bf[n], acc[m][n], 0, 0, 0);
        }
        __syncthreads();
    }

    float* Pp = P + ((size_t)bz * M + row0) * N + col0;
#pragma unroll
    for (int n = 0; n < 4; ++n) {
        const int col = wc * 64 + n * 16 + l15;
#pragma unroll
        for (int m = 0; m < 4; ++m) {
            const int rb = wr * 64 + m * 16 + kh * 4;
#pragma unroll
            for (int i = 0; i < 4; ++i)
                Pp[(size_t)(rb + i) * N + col] = acc[m][n][i];
        }
    }
}

// plain split-K GEMM kernel (layers 1 and 2)
__global__ __launch_bounds__(256) void gemm_splitk(
    const ushort_t* __restrict__ A, const ushort_t* __restrict__ W,
    float* __restrict__ P, int M, int N, int K, int Kc, int nx, int ny)
{
    __shared__ ushort_t As[128 * 64];
    __shared__ ushort_t Ws[128 * 64];
    gemm_body(A, W, P, M, N, K, Kc, nx, ny, blockIdx.x, gridDim.x, As, Ws);
}

// GEMM0 (384 blocks) + W1/W2 split-conversion (6144 blocks) in ONE dispatch:
// the cvt blocks fill the CUs GEMM0 leaves idle.
__global__ __launch_bounds__(256) void gemm0_cvt12(
    const ushort_t* __restrict__ xb, const ushort_t* __restrict__ Wb0,
    float* __restrict__ P,
    const float4* __restrict__ W1, const float4* __restrict__ W2,
    ushort_t* __restrict__ Wb1, ushort_t* __restrict__ Wb2)
{
    __shared__ ushort_t As[128 * 64];
    __shared__ ushort_t Ws[128 * 64];
    const int b = blockIdx.x;
    if (b < 384) {
        gemm_body(xb, Wb0, P, 256, 2048, 1024, 256, 16, 2, b, 384, As, Ws);
    } else if (b < 384 + 4096) {
        do_split(W1, Wb1, (b - 384) * 256 + threadIdx.x, 11);
    } else {
        do_split(W2, Wb2, (b - 4480) * 256 + threadIdx.x, 11);
    }
}

// ---------------- x + W0 split-conversions + ctr zero ----------------
__global__ __launch_bounds__(256) void cvt_xw0(
    const float4* __restrict__ x, const float4* __restrict__ W0,
    ushort_t* __restrict__ xb, ushort_t* __restrict__ Wb0,
    int* __restrict__ ctrs)
{
    const int b = blockIdx.x, tid = threadIdx.x;
    if (b == 0 && tid < 3) ctrs[tid * 16] = 0;
    if (b < 256) do_split(x,  xb,  b * 256 + tid, 10);
    else         do_split(W0, Wb0, (b - 256) * 256 + tid, 10);
}

// ---------------- wave compaction of flagged indices ----------------
__device__ inline void emit(const int* loc, int lc, int* list, int* counter)
{
    const int lane = threadIdx.x & 63;
    int inc = lc;
#pragma unroll
    for (int off = 1; off < 64; off <<= 1) {
        int t = __shfl_up(inc, off);
        if (lane >= off) inc += t;
    }
    const int total = __shfl(inc, 63);
    int base = 0;
    if (lane == 63 && total) base = atomicAdd(counter, total);
    base = __shfl(base, 63);
    const int excl = inc - lc;
    for (int j = 0; j < lc; ++j) {
        int p = base + excl + j;
        if (p < LCAP) list[p] = loc[j];
    }
}

__device__ inline int flag4(float4 v, int e0, int* loc, int lc)
{
    float vv[4] = {v.x, v.y, v.z, v.w};
#pragma unroll
    for (int c = 0; c < 4; ++c)
        if ((fabsf(vv[c] - 1.0f) < SDELTA) || (fabsf(vv[c] - 0.1f) < SDELTA))
            loc[lc++] = e0 + c;
    return lc;
}

__device__ inline void wsplit2(ushort_t* row, int k, float4 v)   // [h|l], width 4096
{
    ushort4 h, l;
    h.x = f2bf(v.x); l.x = f2bf(v.x - bf2f(h.x));
    h.y = f2bf(v.y); l.y = f2bf(v.y - bf2f(h.y));
    h.z = f2bf(v.z); l.z = f2bf(v.z - bf2f(h.z));
    h.w = f2bf(v.w); l.w = f2bf(v.w - bf2f(h.w));
    *reinterpret_cast<ushort4*>(row + k) = h;
    *reinterpret_cast<ushort4*>(row + 2048 + k) = l;
}

__device__ inline void patch2(ushort_t* row, int c, float v)
{
    ushort_t h = f2bf(v);
    ushort_t l = f2bf(v - bf2f(h));
    row[c] = h; row[2048 + c] = l;
}

__device__ inline float4 lifstep(float4 cur, float4 gate)
{
    float4 o;
    o.x = cur.x + ((gate.x > 1.0f) ? 0.9f : 0.0f);
    o.y = cur.y + ((gate.y > 1.0f) ? 0.9f : 0.0f);
    o.z = cur.z + ((gate.z > 1.0f) ? 0.9f : 0.0f);
    o.w = cur.w + ((gate.w > 1.0f) ? 0.9f : 0.0f);
    return o;
}

__device__ inline double wred(double p)
{
#pragma unroll
    for (int off = 32; off; off >>= 1) p += __shfl_down(p, off);
    return __shfl(p, 0);
}

// ---- layer 0 epilogue: reduce S=NS + bias, scan, C0 write, A1 [h|l] ----
__global__ __launch_bounds__(256) void fused0(
    const float4* __restrict__ P, const float* __restrict__ bias,
    float4* __restrict__ C0, ushort_t* __restrict__ A1b,
    int* __restrict__ list, int* __restrict__ counter)
{
    const int i = blockIdx.x * 256 + threadIdx.x;   // < 131072
    float4 s = P[i];
#pragma unroll
    for (int j = 1; j < NS; ++j) {
        float4 t = P[(size_t)j * 131072 + i];
        s.x += t.x; s.y += t.y; s.z += t.z; s.w += t.w;
    }
    const float4 bv = *reinterpret_cast<const float4*>(bias + ((i * 4) & 2047));
    s.x += bv.x; s.y += bv.y; s.z += bv.z; s.w += bv.w;
    C0[i] = s;
    int loc[4];
    int lc = flag4(s, i * 4, loc, 0);
    emit(loc, lc, list, counter);
    float4 mi = lifstep(s, s);
    const int e0 = i * 4, r = e0 >> 11, k = e0 & 2047;
    wsplit2(A1b + (size_t)r * 4096, k, s);
    wsplit2(A1b + (size_t)(256 + r) * 4096, k, mi);
}

// ---- layer 1 epilogue: reduce S=NS both halves, scan, C1, A2 [h|l] ----
__global__ __launch_bounds__(256) void fused1(
    const float4* __restrict__ P, const float* __restrict__ bias,
    float4* __restrict__ C1, ushort_t* __restrict__ A2b,
    int* __restrict__ list, int* __restrict__ counter)
{
    const int i = blockIdx.x * 256 + threadIdx.x;   // < 131072
    float4 c0 = P[i];
    float4 ci = P[131072 + i];
#pragma unroll
    for (int j = 1; j < NS; ++j) {
        float4 t0 = P[(size_t)j * 262144 + i];
        float4 t1 = P[(size_t)j * 262144 + 131072 + i];
        c0.x += t0.x; c0.y += t0.y; c0.z += t0.z; c0.w += t0.w;
        ci.x += t1.x; ci.y += t1.y; ci.z += t1.z; ci.w += t1.w;
    }
    const float4 bv = *reinterpret_cast<const float4*>(bias + ((i * 4) & 2047));
    c0.x += bv.x; c0.y += bv.y; c0.z += bv.z; c0.w += bv.w;
    ci.x += bv.x; ci.y += bv.y; ci.z += bv.z; ci.w += bv.w;
    C1[i] = c0;
    C1[131072 + i] = ci;
    int loc[8];
    int lc = flag4(c0, i * 4, loc, 0);
    lc = flag4(ci, (131072 + i) * 4, loc, lc);
    emit(loc, lc, list, counter);
    float4 m1 = lifstep(ci, c0);
    float4 m2 = lifstep(ci, m1);
    const int e0 = i * 4, r = e0 >> 11, k = e0 & 2047;
    wsplit2(A2b + (size_t)r * 4096, k, c0);
    wsplit2(A2b + (size_t)(256 + r) * 4096, k, m1);
    wsplit2(A2b + (size_t)(512 + r) * 4096, k, m2);
}

// ---- layer 2 epilogue: reduce S=NS + bias + scan -> C2 ----
__global__ __launch_bounds__(256) void reduce_scan2(
    const float4* __restrict__ P, const float* __restrict__ bias,
    float4* __restrict__ C2, int* __restrict__ list, int* __restrict__ counter)
{
    const int i = blockIdx.x * 256 + threadIdx.x;   // < 196608
    float4 s = P[i];
#pragma unroll
    for (int j = 1; j < NS; ++j) {
        float4 t = P[(size_t)j * 196608 + i];
        s.x += t.x; s.y += t.y; s.z += t.z; s.w += t.w;
    }
    const float4 bv = *reinterpret_cast<const float4*>(bias + ((i * 4) & 1023));
    s.x += bv.x; s.y += bv.y; s.z += bv.z; s.w += bv.w;
    C2[i] = s;
    int loc[4];
    int lc = flag4(s, i * 4, loc, 0);
    emit(loc, lc, list, counter);
}

// ---------------- fixups: exact f64 dots, patch C and A [h|l] ----------------
__global__ __launch_bounds__(256) void fixup0(
    float* __restrict__ C0, ushort_t* __restrict__ A1b,
    const float* __restrict__ X, const float* __restrict__ W0,
    const float* __restrict__ b0,
    const int* __restrict__ list, const int* __restrict__ counter)
{
    const int lane = threadIdx.x & 63;
    const int wave = (blockIdx.x * 256 + threadIdx.x) >> 6;
    const int nw = gridDim.x * 4;
    const int nbad = min(*counter, LCAP);
    const int chunk = (nbad + nw - 1) / nw;
    for (int e = wave * chunk; e < min(wave * chunk + chunk, nbad); ++e) {
        const int idx = list[e];
        const int rr = idx >> 11, cc = idx & 2047;
        double p = 0.0;
        for (int k = lane * 4; k < 1024; k += 256) {
            float4 a4 = ld4(X + (size_t)rr * 1024 + k);
            float4 w4 = ld4(W0 + (size_t)cc * 1024 + k);
            p = fma((double)a4.x, (double)w4.x, p);
            p = fma((double)a4.y, (double)w4.y, p);
            p = fma((double)a4.z, (double)w4.z, p);
            p = fma((double)a4.w, (double)w4.w, p);
        }
        const double tot = wred(p);
        if (lane == 0) {
            float c = (float)(tot + (double)b0[cc]);
            C0[idx] = c;
            float mi = c + ((c > 1.0f) ? 0.9f : 0.0f);
            patch2(A1b + (size_t)rr * 4096, cc, c);
            patch2(A1b + (size_t)(256 + rr) * 4096, cc, mi);
        }
    }
}

__global__ __launch_bounds__(256) void fixup1(
    float* __restrict__ C1, ushort_t* __restrict__ A2b,
    const float* __restrict__ C0, const float* __restrict__ W1,
    const float* __restrict__ b1,
    const int* __restrict__ list, const int* __restrict__ counter)
{
    const int lane = threadIdx.x & 63;
    const int wave = (blockIdx.x * 256 + threadIdx.x) >> 6;
    const int nw = gridDim.x * 4;
    const int nbad = min(*counter, LCAP);
    const int chunk = (nbad + nw - 1) / nw;
    for (int e = wave * chunk; e < min(wave * chunk + chunk, nbad); ++e) {
        const int idx = list[e];
        const int rr = idx >> 11, cc = idx & 2047;
        const int rp = rr & 255;
        double p0 = 0.0, p1 = 0.0;
        for (int k = lane * 4; k < 2048; k += 256) {
            float4 a4 = ld4(C0 + (size_t)rp * 2048 + k);   // mem0(0) row
            float4 w4 = ld4(W1 + (size_t)cc * 2048 + k);
            float4 b4 = lifstep(a4, a4);                    // mem0(inf) row
            p0 = fma((double)a4.x, (double)w4.x, p0);
            p0 = fma((double)a4.y, (double)w4.y, p0);
            p0 = fma((double)a4.z, (double)w4.z, p0);
            p0 = fma((double)a4.w, (double)w4.w, p0);
            p1 = fma((double)b4.x, (double)w4.x, p1);
            p1 = fma((double)b4.y, (double)w4.y, p1);
            p1 = fma((double)b4.z, (double)w4.z, p1);
            p1 = fma((double)b4.w, (double)w4.w, p1);
        }
        const double t0 = wred(p0);
        const double t1 = wred(p1);
        if (lane == 0) {
            float c0 = (float)(t0 + (double)b1[cc]);
            float ci = (float)(t1 + (double)b1[cc]);
            C1[(size_t)rp * 2048 + cc] = c0;
            C1[(size_t)(256 + rp) * 2048 + cc] = ci;
            float m1 = ci + ((c0 > 1.0f) ? 0.9f : 0.0f);
            float m2 = ci + ((m1 > 1.0f) ? 0.9f : 0.0f);
            patch2(A2b + (size_t)rp * 4096, cc, c0);
            patch2(A2b + (size_t)(256 + rp) * 4096, cc, m1);
            patch2(A2b + (size_t)(512 + rp) * 4096, cc, m2);
        }
    }
}

__global__ __launch_bounds__(256) void fixup2(
    float* __restrict__ C2, const float* __restrict__ C1,
    const float* __restrict__ W2, const float* __restrict__ b2,
    const int* __restrict__ list, const int* __restrict__ counter)
{
    const int lane = threadIdx.x & 63;
    const int wave = (blockIdx.x * 256 + threadIdx.x) >> 6;
    const int nw = gridDim.x * 4;
    const int nbad = min(*counter, LCAP);
    const int chunk = (nbad + nw - 1) / nw;
    for (int e = wave * chunk; e < min(wave * chunk + chunk, nbad); ++e) {
        const int idx = list[e];
        const int rr = idx >> 10, cc = idx & 1023;
        const int rp = rr & 255;
        double pA = 0.0, pB = 0.0, pC = 0.0;
        for (int k = lane * 4; k < 2048; k += 256) {
            float4 c04 = ld4(C1 + (size_t)rp * 2048 + k);
            float4 ci4 = ld4(C1 + (size_t)(256 + rp) * 2048 + k);
            float4 w4  = ld4(W2 + (size_t)cc * 2048 + k);
            float4 m14 = lifstep(ci4, c04);
            float4 m24 = lifstep(ci4, m14);
            pA = fma((double)c04.x, (double)w4.x, pA);
            pA = fma((double)c04.y, (double)w4.y, pA);
            pA = fma((double)c04.z, (double)w4.z, pA);
            pA = fma((double)c04.w, (double)w4.w, pA);
            pB = fma((double)m14.x, (double)w4.x, pB);
            pB = fma((double)m14.y, (double)w4.y, pB);
            pB = fma((double)m14.z, (double)w4.z, pB);
            pB = fma((double)m14.w, (double)w4.w, pB);
            pC = fma((double)m24.x, (double)w4.x, pC);
            pC = fma((double)m24.y, (double)w4.y, pC);
            pC = fma((double)m24.z, (double)w4.z, pC);
            pC = fma((double)m24.w, (double)w4.w, pC);
        }
        const double tA = wred(pA);
        const double tB = wred(pB);
        const double tC = wred(pC);
        if (lane == 0) {
            C2[(size_t)rp * 1024 + cc]         = (float)(tA + (double)b2[cc]);
            C2[(size_t)(256 + rp) * 1024 + cc] = (float)(tB + (double)b2[cc]);
            C2[(size_t)(512 + rp) * 1024 + cc] = (float)(tC + (double)b2[cc]);
        }
    }
}

// Final layer + broadcast; grid.y covers 4 time-slices each.
__global__ __launch_bounds__(256) void lif2_bcast(const float4* __restrict__ c2,
                                                  float4* __restrict__ out, int n4)
{
    int i = blockIdx.x * 256 + threadIdx.x;
    if (i >= n4) return;
    float4 c0 = c2[i], c1 = c2[n4 + i], ci = c2[2 * n4 + i];
    float4 m0 = c0;
    float4 m1 = lifstep(c1, m0);
    float4 m2 = lifstep(ci, m1);
    float4 m3 = lifstep(ci, m2);
    int t0 = blockIdx.y * 4;
#pragma unroll
    for (int j = 0; j < 4; ++j) {
        int t = t0 + j;
        float4 v = (t == 0) ? m0 : (t == 1) ? m1 : (t == 2) ? m2 : m3;
        out[(size_t)t * n4 + i] = v;
    }
}

extern "C" void kernel_launch(void* const* d_in, const int* in_sizes, int n_in,
                              void* d_out, int out_size, void* d_ws, size_t ws_size,
                              hipStream_t stream)
{
    const float* x  = (const float*)d_in[0];  // [256,1024]
    const float* W0 = (const float*)d_in[1];  // [2048,1024]
    const float* b0 = (const float*)d_in[2];
    const float* W1 = (const float*)d_in[3];  // [2048,2048]
    const float* b1 = (const float*)d_in[4];
    const float* W2 = (const float*)d_in[5];  // [1024,2048]
    const float* b2 = (const float*)d_in[6];
    float* out = (float*)d_out;
    float* ws  = (float*)d_ws;

    // ws (floats): C0 0.5M | C1 1M | C2 0.75M | ctrs | lists 3x64K
    float* C0 = ws;
    float* C1 = ws + 524288;
    float* C2 = ws + 1572864;
    int* ctrs  = (int*)(ws + 2359296);
    int* list0 = (int*)(ws + 2359360);
    int* list1 = (int*)(ws + 2424896);
    int* list2 = (int*)(ws + 2490432);

    // d_out scratch (ALL overwritten by lif2_bcast at the end), float offsets:
    ushort_t* Wb0 = (ushort_t*)(out);               // [2048,2048] bf16 = 2M floats
    ushort_t* Wb1 = (ushort_t*)(out + 2097152);     // [2048,4096] bf16 = 4M floats
    ushort_t* Wb2 = (ushort_t*)(out + 6291456);     // [1024,4096] bf16 = 2M floats
    ushort_t* xb  = (ushort_t*)(out + 8388608);     // [256,2048]  bf16 = 256K floats
    ushort_t* A1b = (ushort_t*)(out + 8650752);     // [512,4096]  bf16 = 1M floats
    ushort_t* A2b = (ushort_t*)(out + 9699328);     // [768,4096]  bf16 = 1.5M floats
    float* Pbuf   = out + 11272192;                 // partials, max 12.6M -> 23.9M < 26.2M

    dim3 blk(256);

    // 1: x + W0 conversions + counter zeroing (GEMM0's inputs only)
    cvt_xw0<<<dim3(2304), blk, 0, stream>>>((const float4*)x, (const float4*)W0,
                                            xb, Wb0, ctrs);

    // 2: GEMM0 (384 blocks, K'=3072 Kc=256 S=12) + W1/W2 conversion overlap
    gemm0_cvt12<<<dim3(6528), blk, 0, stream>>>(xb, Wb0, Pbuf,
                                                (const float4*)W1, (const float4*)W2,
                                                Wb1, Wb2);
    fused0<<<dim3(512), blk, 0, stream>>>((const float4*)Pbuf, b0, (float4*)C0,
                                          A1b, list0, ctrs + 0);
    fixup0<<<dim3(256), blk, 0, stream>>>(C0, A1b, x, W0, b0, list0, ctrs + 0);

    // layer 1. K'=6144, Kc=512, S=12 -> 16x4x12 = 768 blocks (3/CU)
    gemm_splitk<<<dim3(768), blk, 0, stream>>>(A1b, Wb1, Pbuf, 512, 2048, 2048, 512, 16, 4);
    fused1<<<dim3(512), blk, 0, stream>>>((const float4*)Pbuf, b1, (float4*)C1,
                                          A2b, list1, ctrs + 16);
    fixup1<<<dim3(256), blk, 0, stream>>>(C1, A2b, C0, W1, b1, list1, ctrs + 16);

    // layer 2. K'=6144, Kc=512, S=12 -> 8x6x12 = 576 blocks
    gemm_splitk<<<dim3(576), blk, 0, stream>>>(A2b, Wb2, Pbuf, 768, 1024, 2048, 512, 8, 6);
    reduce_scan2<<<dim3(768), blk, 0, stream>>>((const float4*)Pbuf, b2, (float4*)C2,
                                                list2, ctrs + 32);
    fixup2<<<dim3(256), blk, 0, stream>>>(C2, C1, W2, b2, list2, ctrs + 32);

    // layer-2 LIF chain + output broadcast (overwrites all of d_out)
    lif2_bcast<<<dim3(256, 25), blk, 0, stream>>>((const float4*)C2, (float4*)out, 65536);
}

// Round 20
// 145.686 us; speedup vs baseline: 1.2937x; 1.2466x over previous
//
#include <hip/hip_runtime.h>

// SNN with "swapped outputs" bug: stored state = spike (binary), forwarded
// value = membrane. reset = (spk_prev > 1) == 0 always -> mem = cur + 0.9*spk_prev.
// Constant input -> spike patterns fixate: mem0 const t>=1, mem1 t>=2, out t>=3.
// GEMM0 (256x2048,K=1024); GEMM1 {mem0(0),mem0(inf)} (M=512,K=2048);
// GEMM2 {mem1(0),mem1(1),mem1(inf)} (M=768,N=1024,K=2048); broadcast t>=3.
// Split-bf16 [h|l]: Ah.Wh + Ah.Wl + Al.Wh as one logical K'=3K GEMM; err ~1e-5.
// f64 fixup of elements within SDELTA=1e-3 of decision points -> exact decisions.
//
// Round-19 (181.6us): W1/W2-cvt overlapped into GEMM0 dispatch. Round 20:
// fixups merged INTO the epilogues via block-local LDS lists (each flagged
// element's fix writes only block-owned memory; fused2 restructured so thread
// i owns all 3 variants to kill the cross-block hazard). 10 -> 8 dispatches;
// global lists/counters deleted. Numerics bit-identical.

typedef unsigned short ushort_t;
typedef __attribute__((ext_vector_type(8))) short bf16x8;
typedef __attribute__((ext_vector_type(4))) float f32x4;

#define SDELTA 1.0e-3f
#define NS 12   // split-K factor

__device__ inline ushort_t f2bf(float f) {       // RNE f32 -> bf16
    unsigned u = __float_as_uint(f);
    u += 0x7FFFu + ((u >> 16) & 1u);
    return (ushort_t)(u >> 16);
}
__device__ inline float bf2f(ushort_t h) { return __uint_as_float((unsigned)h << 16); }
__device__ inline float4 ld4(const float* p) { return *reinterpret_cast<const float4*>(p); }

__device__ inline void gload16(const void* g, void* l) {
    __builtin_amdgcn_global_load_lds(
        (__attribute__((address_space(1))) void*)g,
        (__attribute__((address_space(3))) void*)l, 16, 0, 0);
}

__device__ inline void do_split(const float4* src, ushort_t* dst, int i, int logK)
{
    float4 v = src[i];
    const int K = 1 << logK;
    const int e0 = i * 4;
    const int r = e0 >> logK, k = e0 & (K - 1);
    ushort_t* row = dst + (size_t)r * 2 * K;
    ushort4 h, l;
    h.x = f2bf(v.x); l.x = f2bf(v.x - bf2f(h.x));
    h.y = f2bf(v.y); l.y = f2bf(v.y - bf2f(h.y));
    h.z = f2bf(v.z); l.z = f2bf(v.z - bf2f(h.z));
    h.w = f2bf(v.w); l.w = f2bf(v.w - bf2f(h.w));
    *reinterpret_cast<ushort4*>(row + k) = h;
    *reinterpret_cast<ushort4*>(row + K + k) = l;
}

// ---- GEMM core: 128x128 split-K over logical K'=3K, physical [h|l] ----
// LDS: linear dest (gload_lds), XOR-swizzled global source column, XOR reads.
__device__ __attribute__((always_inline)) inline void gemm_body(
    const ushort_t* __restrict__ A, const ushort_t* __restrict__ W,
    float* __restrict__ P, int M, int N, int K, int Kc, int nx, int ny,
    int lin, int nwg, ushort_t* As, ushort_t* Ws)
{
    const int swzb = (lin & 7) * (nwg >> 3) + (lin >> 3);
    const int nxy = nx * ny;
    const int bz  = swzb / nxy;
    const int rem = swzb - bz * nxy;
    const int by  = rem / nx;
    const int bx  = rem - by * nx;

    const int tid  = threadIdx.x;
    const int lane = tid & 63;
    const int wid  = tid >> 6;
    const int row0 = by * 128;
    const int col0 = bx * 128;
    const int k0   = bz * Kc;          // logical k in [0, 3K)
    const int st   = 2 * K;            // physical row stride
    const int aoff = (k0 < K) ? k0 : (k0 - K);           // A logical [h,h,l]
    const int woff = (k0 < 2 * K) ? k0 : (k0 - 2 * K);   // W logical [h,l,h]

    const int srow = wid * 32 + (lane >> 3);
    const int scol = (((lane & 7) ^ ((lane >> 3) & 7))) * 8;
    const ushort_t* Ag = A + (size_t)(row0 + srow) * st + aoff + scol;
    const ushort_t* Wg = W + (size_t)(col0 + srow) * st + woff + scol;

    const int wr = wid >> 1, wc = wid & 1;
    const int l15 = lane & 15;
    const int kh  = lane >> 4;
    const int swz8 = l15 & 7;
    const int ch0 = ((kh + 0) ^ swz8) * 8;
    const int ch1 = ((kh + 4) ^ swz8) * 8;
    int aRow[4], bRow[4];
#pragma unroll
    for (int m = 0; m < 4; ++m) aRow[m] = (wr * 64 + m * 16 + l15) * 64;
#pragma unroll
    for (int n = 0; n < 4; ++n) bRow[n] = (wc * 64 + n * 16 + l15) * 64;

    f32x4 acc[4][4] = {};
    const int NIT = Kc / 64;

    for (int it = 0; it < NIT; ++it) {
        const int kk = it * 64;
#pragma unroll
        for (int i = 0; i < 4; ++i) {
            gload16(Ag + (size_t)(i * 8) * st + kk, &As[(wid * 32 + i * 8) * 64]);
            gload16(Wg + (size_t)(i * 8) * st + kk, &Ws[(wid * 32 + i * 8) * 64]);
        }
        __syncthreads();
#pragma unroll
        for (int ks = 0; ks < 2; ++ks) {
            const int ch = ks ? ch1 : ch0;
            bf16x8 af[4], bf[4];
#pragma unroll
            for (int m = 0; m < 4; ++m)
                af[m] = *reinterpret_cast<const bf16x8*>(&As[aRow[m] + ch]);
#pragma unroll
            for (int n = 0; n < 4; ++n)
                bf[n] = *reinterpret_cast<const bf16x8*>(&Ws[bRow[n] + ch]);
#pragma unroll
            for (int m = 0; m < 4; ++m)
#pragma unroll
                for (int n = 0; n < 4; ++n)
                    acc[m][n] = __builtin_amdgcn_mfma_f32_16x16x32_bf16(
                        af[m], bf[n], acc[m][n], 0, 0, 0);
        }
        __syncthreads();
    }

    float* Pp = P + ((size_t)bz * M + row0) * N + col0;
#pragma unroll
    for (int n = 0; n < 4; ++n) {
        const int col = wc * 64 + n * 16 + l15;
#pragma unroll
        for (int m = 0; m < 4; ++m) {
            const int rb = wr * 64 + m * 16 + kh * 4;
#pragma unroll
            for (int i = 0; i < 4; ++i)
                Pp[(size_t)(rb + i) * N + col] = acc[m][n][i];
        }
    }
}

// plain split-K GEMM kernel (layers 1 and 2)
__global__ __launch_bounds__(256) void gemm_splitk(
    const ushort_t* __restrict__ A, const ushort_t* __restrict__ W,
    float* __restrict__ P, int M, int N, int K, int Kc, int nx, int ny)
{
    __shared__ ushort_t As[128 * 64];
    __shared__ ushort_t Ws[128 * 64];
    gemm_body(A, W, P, M, N, K, Kc, nx, ny, blockIdx.x, gridDim.x, As, Ws);
}

// GEMM0 (384 blocks) + W1/W2 split-conversion (6144 blocks) in ONE dispatch.
__global__ __launch_bounds__(256) void gemm0_cvt12(
    const ushort_t* __restrict__ xb, const ushort_t* __restrict__ Wb0,
    float* __restrict__ P,
    const float4* __restrict__ W1, const float4* __restrict__ W2,
    ushort_t* __restrict__ Wb1, ushort_t* __restrict__ Wb2)
{
    __shared__ ushort_t As[128 * 64];
    __shared__ ushort_t Ws[128 * 64];
    const int b = blockIdx.x;
    if (b < 384) {
        gemm_body(xb, Wb0, P, 256, 2048, 1024, 256, 16, 2, b, 384, As, Ws);
    } else if (b < 384 + 4096) {
        do_split(W1, Wb1, (b - 384) * 256 + threadIdx.x, 11);
    } else {
        do_split(W2, Wb2, (b - 4480) * 256 + threadIdx.x, 11);
    }
}

// ---------------- x + W0 split-conversions ----------------
__global__ __launch_bounds__(256) void cvt_xw0(
    const float4* __restrict__ x, const float4* __restrict__ W0,
    ushort_t* __restrict__ xb, ushort_t* __restrict__ Wb0)
{
    const int b = blockIdx.x, tid = threadIdx.x;
    if (b < 256) do_split(x,  xb,  b * 256 + tid, 10);
    else         do_split(W0, Wb0, (b - 256) * 256 + tid, 10);
}

// ---------------- helpers ----------------
__device__ inline int flag4(float4 v, int e0, int* loc, int lc)
{
    float vv[4] = {v.x, v.y, v.z, v.w};
#pragma unroll
    for (int c = 0; c < 4; ++c)
        if ((fabsf(vv[c] - 1.0f) < SDELTA) || (fabsf(vv[c] - 0.1f) < SDELTA))
            loc[lc++] = e0 + c;
    return lc;
}

__device__ inline void wsplit2(ushort_t* row, int k, float4 v)   // [h|l], width 4096
{
    ushort4 h, l;
    h.x = f2bf(v.x); l.x = f2bf(v.x - bf2f(h.x));
    h.y = f2bf(v.y); l.y = f2bf(v.y - bf2f(h.y));
    h.z = f2bf(v.z); l.z = f2bf(v.z - bf2f(h.z));
    h.w = f2bf(v.w); l.w = f2bf(v.w - bf2f(h.w));
    *reinterpret_cast<ushort4*>(row + k) = h;
    *reinterpret_cast<ushort4*>(row + 2048 + k) = l;
}

__device__ inline void patch2(ushort_t* row, int c, float v)
{
    ushort_t h = f2bf(v);
    ushort_t l = f2bf(v - bf2f(h));
    row[c] = h; row[2048 + c] = l;
}

__device__ inline float4 lifstep(float4 cur, float4 gate)
{
    float4 o;
    o.x = cur.x + ((gate.x > 1.0f) ? 0.9f : 0.0f);
    o.y = cur.y + ((gate.y > 1.0f) ? 0.9f : 0.0f);
    o.z = cur.z + ((gate.z > 1.0f) ? 0.9f : 0.0f);
    o.w = cur.w + ((gate.w > 1.0f) ? 0.9f : 0.0f);
    return o;
}

__device__ inline double wred(double p)
{
#pragma unroll
    for (int off = 32; off; off >>= 1) p += __shfl_down(p, off);
    return __shfl(p, 0);
}

// ---- layer 0: reduce + bias + C0 + A1 [h|l] + IN-BLOCK f64 fixup ----
__global__ __launch_bounds__(256) void fused0(
    const float4* __restrict__ P, const float* __restrict__ bias,
    float* __restrict__ C0f, ushort_t* __restrict__ A1b,
    const float* __restrict__ X, const float* __restrict__ W0,
    const float* __restrict__ b0f)
{
    __shared__ int flist[1024];
    __shared__ int fcnt;
    if (threadIdx.x == 0) fcnt = 0;
    __syncthreads();

    const int i = blockIdx.x * 256 + threadIdx.x;   // < 131072
    float4 s = P[i];
#pragma unroll
    for (int j = 1; j < NS; ++j) {
        float4 t = P[(size_t)j * 131072 + i];
        s.x += t.x; s.y += t.y; s.z += t.z; s.w += t.w;
    }
    const float4 bv = *reinterpret_cast<const float4*>(bias + ((i * 4) & 2047));
    s.x += bv.x; s.y += bv.y; s.z += bv.z; s.w += bv.w;
    reinterpret_cast<float4*>(C0f)[i] = s;
    int loc[4];
    int lc = flag4(s, i * 4, loc, 0);
    for (int j = 0; j < lc; ++j) { int p = atomicAdd(&fcnt, 1); flist[p] = loc[j]; }
    float4 mi = lifstep(s, s);
    const int e0 = i * 4, r = e0 >> 11, k = e0 & 2047;
    wsplit2(A1b + (size_t)r * 4096, k, s);
    wsplit2(A1b + (size_t)(256 + r) * 4096, k, mi);
    __syncthreads();

    // in-block exact fixup (all writes block-owned)
    const int lane = threadIdx.x & 63;
    const int wid  = threadIdx.x >> 6;
    for (int e = wid; e < fcnt; e += 4) {
        const int idx = flist[e];
        const int rr = idx >> 11, cc = idx & 2047;
        double p = 0.0;
        for (int kk = lane * 4; kk < 1024; kk += 256) {
            float4 a4 = ld4(X + (size_t)rr * 1024 + kk);
            float4 w4 = ld4(W0 + (size_t)cc * 1024 + kk);
            p = fma((double)a4.x, (double)w4.x, p);
            p = fma((double)a4.y, (double)w4.y, p);
            p = fma((double)a4.z, (double)w4.z, p);
            p = fma((double)a4.w, (double)w4.w, p);
        }
        const double tot = wred(p);
        if (lane == 0) {
            float c = (float)(tot + (double)b0f[cc]);
            C0f[idx] = c;
            float mi2 = c + ((c > 1.0f) ? 0.9f : 0.0f);
            patch2(A1b + (size_t)rr * 4096, cc, c);
            patch2(A1b + (size_t)(256 + rr) * 4096, cc, mi2);
        }
    }
}

// ---- layer 1: reduce both halves + C1 + A2 [h|l] + IN-BLOCK f64 fixup ----
__global__ __launch_bounds__(256) void fused1(
    const float4* __restrict__ P, const float* __restrict__ bias,
    float* __restrict__ C1f, ushort_t* __restrict__ A2b,
    const float* __restrict__ C0, const float* __restrict__ W1)
{
    __shared__ int flist[2048];
    __shared__ int fcnt;
    if (threadIdx.x == 0) fcnt = 0;
    __syncthreads();

    const int i = blockIdx.x * 256 + threadIdx.x;   // < 131072
    float4* C1 = reinterpret_cast<float4*>(C1f);
    float4 c0 = P[i];
    float4 ci = P[131072 + i];
#pragma unroll
    for (int j = 1; j < NS; ++j) {
        float4 t0 = P[(size_t)j * 262144 + i];
        float4 t1 = P[(size_t)j * 262144 + 131072 + i];
        c0.x += t0.x; c0.y += t0.y; c0.z += t0.z; c0.w += t0.w;
        ci.x += t1.x; ci.y += t1.y; ci.z += t1.z; ci.w += t1.w;
    }
    const float4 bv = *reinterpret_cast<const float4*>(bias + ((i * 4) & 2047));
    c0.x += bv.x; c0.y += bv.y; c0.z += bv.z; c0.w += bv.w;
    ci.x += bv.x; ci.y += bv.y; ci.z += bv.z; ci.w += bv.w;
    C1[i] = c0;
    C1[131072 + i] = ci;
    int loc[8];
    int lc = flag4(c0, i * 4, loc, 0);
    lc = flag4(ci, (131072 + i) * 4, loc, lc);
    for (int j = 0; j < lc; ++j) { int p = atomicAdd(&fcnt, 1); flist[p] = loc[j]; }
    float4 m1 = lifstep(ci, c0);
    float4 m2 = lifstep(ci, m1);
    const int e0 = i * 4, r = e0 >> 11, k = e0 & 2047;
    wsplit2(A2b + (size_t)r * 4096, k, c0);
    wsplit2(A2b + (size_t)(256 + r) * 4096, k, m1);
    wsplit2(A2b + (size_t)(512 + r) * 4096, k, m2);
    __syncthreads();

    const int lane = threadIdx.x & 63;
    const int wid  = threadIdx.x >> 6;
    for (int e = wid; e < fcnt; e += 4) {
        const int idx = flist[e];
        const int cc = idx & 2047;
        const int rp = (idx >> 11) & 255;
        double p0 = 0.0, p1 = 0.0;
        for (int kk = lane * 4; kk < 2048; kk += 256) {
            float4 a4 = ld4(C0 + (size_t)rp * 2048 + kk);   // mem0(0) row
            float4 w4 = ld4(W1 + (size_t)cc * 2048 + kk);
            float4 b4 = lifstep(a4, a4);                     // mem0(inf) row
            p0 = fma((double)a4.x, (double)w4.x, p0);
            p0 = fma((double)a4.y, (double)w4.y, p0);
            p0 = fma((double)a4.z, (double)w4.z, p0);
            p0 = fma((double)a4.w, (double)w4.w, p0);
            p1 = fma((double)b4.x, (double)w4.x, p1);
            p1 = fma((double)b4.y, (double)w4.y, p1);
            p1 = fma((double)b4.z, (double)w4.z, p1);
            p1 = fma((double)b4.w, (double)w4.w, p1);
        }
        const double t0 = wred(p0);
        const double t1 = wred(p1);
        if (lane == 0) {
            float fc0 = (float)(t0 + (double)bias[cc]);
            float fci = (float)(t1 + (double)bias[cc]);
            C1f[(size_t)rp * 2048 + cc] = fc0;
            C1f[(size_t)(256 + rp) * 2048 + cc] = fci;
            float m1s = fci + ((fc0 > 1.0f) ? 0.9f : 0.0f);
            float m2s = fci + ((m1s > 1.0f) ? 0.9f : 0.0f);
            patch2(A2b + (size_t)rp * 4096, cc, fc0);
            patch2(A2b + (size_t)(256 + rp) * 4096, cc, m1s);
            patch2(A2b + (size_t)(512 + rp) * 4096, cc, m2s);
        }
    }
}

// ---- layer 2: thread i owns ALL 3 variants (i, 65536+i, 131072+i) so the
// in-block fixup's writes stay block-owned; reduce + bias + scan + f64 fixup ----
__global__ __launch_bounds__(256) void fused2(
    const float4* __restrict__ P, const float* __restrict__ bias,
    float* __restrict__ C2f, const float* __restrict__ C1,
    const float* __restrict__ W2)
{
    __shared__ int flist[3072];
    __shared__ int fcnt;
    if (threadIdx.x == 0) fcnt = 0;
    __syncthreads();

    const int i = blockIdx.x * 256 + threadIdx.x;   // < 65536
    float4* C2 = reinterpret_cast<float4*>(C2f);
    const float4 bv = *reinterpret_cast<const float4*>(bias + ((i * 4) & 1023));
#pragma unroll
    for (int v = 0; v < 3; ++v) {
        float4 s = P[(size_t)v * 65536 + i];
#pragma unroll
        for (int j = 1; j < NS; ++j) {
            float4 t = P[(size_t)j * 196608 + (size_t)v * 65536 + i];
            s.x += t.x; s.y += t.y; s.z += t.z; s.w += t.w;
        }
        s.x += bv.x; s.y += bv.y; s.z += bv.z; s.w += bv.w;
        C2[(size_t)v * 65536 + i] = s;
        int loc[4];
        int lc = flag4(s, (v * 65536 + i) * 4, loc, 0);
        for (int j = 0; j < lc; ++j) { int p = atomicAdd(&fcnt, 1); flist[p] = loc[j]; }
    }
    __syncthreads();

    const int lane = threadIdx.x & 63;
    const int wid  = threadIdx.x >> 6;
    for (int e = wid; e < fcnt; e += 4) {
        const int idx = flist[e];
        const int cc = idx & 1023;
        const int rp = (idx >> 10) & 255;
        double pA = 0.0, pB = 0.0, pC = 0.0;
        for (int kk = lane * 4; kk < 2048; kk += 256) {
            float4 c04 = ld4(C1 + (size_t)rp * 2048 + kk);
            float4 ci4 = ld4(C1 + (size_t)(256 + rp) * 2048 + kk);
            float4 w4  = ld4(W2 + (size_t)cc * 2048 + kk);
            float4 m14 = lifstep(ci4, c04);
            float4 m24 = lifstep(ci4, m14);
            pA = fma((double)c04.x, (double)w4.x, pA);
            pA = fma((double)c04.y, (double)w4.y, pA);
            pA = fma((double)c04.z, (double)w4.z, pA);
            pA = fma((double)c04.w, (double)w4.w, pA);
            pB = fma((double)m14.x, (double)w4.x, pB);
            pB = fma((double)m14.y, (double)w4.y, pB);
            pB = fma((double)m14.z, (double)w4.z, pB);
            pB = fma((double)m14.w, (double)w4.w, pB);
            pC = fma((double)m24.x, (double)w4.x, pC);
            pC = fma((double)m24.y, (double)w4.y, pC);
            pC = fma((double)m24.z, (double)w4.z, pC);
            pC = fma((double)m24.w, (double)w4.w, pC);
        }
        const double tA = wred(pA);
        const double tB = wred(pB);
        const double tC = wred(pC);
        if (lane == 0) {
            C2f[(size_t)rp * 1024 + cc]         = (float)(tA + (double)bias[cc]);
            C2f[(size_t)(256 + rp) * 1024 + cc] = (float)(tB + (double)bias[cc]);
            C2f[(size_t)(512 + rp) * 1024 + cc] = (float)(tC + (double)bias[cc]);
        }
    }
}

// Final layer + broadcast; grid.y covers 4 time-slices each.
__global__ __launch_bounds__(256) void lif2_bcast(const float4* __restrict__ c2,
                                                  float4* __restrict__ out, int n4)
{
    int i = blockIdx.x * 256 + threadIdx.x;
    if (i >= n4) return;
    float4 c0 = c2[i], c1 = c2[n4 + i], ci = c2[2 * n4 + i];
    float4 m0 = c0;
    float4 m1 = lifstep(c1, m0);
    float4 m2 = lifstep(ci, m1);
    float4 m3 = lifstep(ci, m2);
    int t0 = blockIdx.y * 4;
#pragma unroll
    for (int j = 0; j < 4; ++j) {
        int t = t0 + j;
        float4 v = (t == 0) ? m0 : (t == 1) ? m1 : (t == 2) ? m2 : m3;
        out[(size_t)t * n4 + i] = v;
    }
}

extern "C" void kernel_launch(void* const* d_in, const int* in_sizes, int n_in,
                              void* d_out, int out_size, void* d_ws, size_t ws_size,
                              hipStream_t stream)
{
    const float* x  = (const float*)d_in[0];  // [256,1024]
    const float* W0 = (const float*)d_in[1];  // [2048,1024]
    const float* b0 = (const float*)d_in[2];
    const float* W1 = (const float*)d_in[3];  // [2048,2048]
    const float* b1 = (const float*)d_in[4];
    const float* W2 = (const float*)d_in[5];  // [1024,2048]
    const float* b2 = (const float*)d_in[6];
    float* out = (float*)d_out;
    float* ws  = (float*)d_ws;

    // ws (floats): C0 0.5M | C1 1M | C2 0.75M
    float* C0 = ws;
    float* C1 = ws + 524288;
    float* C2 = ws + 1572864;

    // d_out scratch (ALL overwritten by lif2_bcast at the end), float offsets:
    ushort_t* Wb0 = (ushort_t*)(out);               // [2048,2048] bf16 = 2M floats
    ushort_t* Wb1 = (ushort_t*)(out + 2097152);     // [2048,4096] bf16 = 4M floats
    ushort_t* Wb2 = (ushort_t*)(out + 6291456);     // [1024,4096] bf16 = 2M floats
    ushort_t* xb  = (ushort_t*)(out + 8388608);     // [256,2048]  bf16 = 256K floats
    ushort_t* A1b = (ushort_t*)(out + 8650752);     // [512,4096]  bf16 = 1M floats
    ushort_t* A2b = (ushort_t*)(out + 9699328);     // [768,4096]  bf16 = 1.5M floats
    float* Pbuf   = out + 11272192;                 // partials, max 12.6M -> 23.9M < 26.2M

    dim3 blk(256);

    // 1: x + W0 conversions (GEMM0's inputs only)
    cvt_xw0<<<dim3(2304), blk, 0, stream>>>((const float4*)x, (const float4*)W0,
                                            xb, Wb0);

    // 2: GEMM0 (384 blocks, K'=3072 Kc=256 S=12) + W1/W2 conversion overlap
    gemm0_cvt12<<<dim3(6528), blk, 0, stream>>>(xb, Wb0, Pbuf,
                                                (const float4*)W1, (const float4*)W2,
                                                Wb1, Wb2);
    // 3: layer-0 epilogue + in-block fixup
    fused0<<<dim3(512), blk, 0, stream>>>((const float4*)Pbuf, b0, C0,
                                          A1b, x, W0, b0);

    // 4: GEMM1. K'=6144, Kc=512, S=12 -> 16x4x12 = 768 blocks (3/CU)
    gemm_splitk<<<dim3(768), blk, 0, stream>>>(A1b, Wb1, Pbuf, 512, 2048, 2048, 512, 16, 4);
    // 5: layer-1 epilogue + in-block fixup
    fused1<<<dim3(512), blk, 0, stream>>>((const float4*)Pbuf, b1, C1,
                                          A2b, C0, W1);

    // 6: GEMM2. K'=6144, Kc=512, S=12 -> 8x6x12 = 576 blocks
    gemm_splitk<<<dim3(576), blk, 0, stream>>>(A2b, Wb2, Pbuf, 768, 1024, 2048, 512, 8, 6);
    // 7: layer-2 epilogue + in-block fixup (thread owns all 3 variants)
    fused2<<<dim3(256), blk, 0, stream>>>((const float4*)Pbuf, b2, C2, C1, W2);

    // 8: layer-2 LIF chain + output broadcast (overwrites all of d_out)
    lif2_bcast<<<dim3(256, 25), blk, 0, stream>>>((const float4*)C2, (float4*)out, 65536);
}

// Round 21
// 142.848 us; speedup vs baseline: 1.3194x; 1.0199x over previous
//
#include <hip/hip_runtime.h>

// SNN with "swapped outputs" bug: stored state = spike (binary), forwarded
// value = membrane. reset = (spk_prev > 1) == 0 always -> mem = cur + 0.9*spk_prev.
// Constant input -> spike patterns fixate: mem0 const t>=1, mem1 t>=2, out t>=3.
// GEMM0 (256x2048,K=1024); GEMM1 {mem0(0),mem0(inf)} (M=512,K=2048);
// GEMM2 {mem1(0),mem1(1),mem1(inf)} (M=768,N=1024,K=2048); broadcast t>=3.
// Split-bf16 [h|l]: Ah.Wh + Ah.Wl + Al.Wh as one logical K'=3K GEMM; err ~1e-5.
// f64 in-block fixup of elements within SDELTA=1e-3 of decision points.
//
// Round-20 (145.7us): in-block fixups saved ~36us -> dispatch boundaries cost
// ~8-12us each. Round 21: merge the 105MB broadcast into fused2. GEMM2
// partials (S=6 = 4.72M floats) live in d_out's t>=80 tail; fused2_bcast
// writes only t=0..79 (race-free), then a tiny tail_bcast writes t=80..99.

typedef unsigned short ushort_t;
typedef __attribute__((ext_vector_type(8))) short bf16x8;
typedef __attribute__((ext_vector_type(4))) float f32x4;

#define SDELTA 1.0e-3f
#define NS 12   // split-K for GEMM0/GEMM1
#define NS2 6   // split-K for GEMM2 (partials must fit the t>=80 tail)

__device__ inline ushort_t f2bf(float f) {       // RNE f32 -> bf16
    unsigned u = __float_as_uint(f);
    u += 0x7FFFu + ((u >> 16) & 1u);
    return (ushort_t)(u >> 16);
}
__device__ inline float bf2f(ushort_t h) { return __uint_as_float((unsigned)h << 16); }
__device__ inline float4 ld4(const float* p) { return *reinterpret_cast<const float4*>(p); }

__device__ inline void gload16(const void* g, void* l) {
    __builtin_amdgcn_global_load_lds(
        (__attribute__((address_space(1))) void*)g,
        (__attribute__((address_space(3))) void*)l, 16, 0, 0);
}

__device__ inline void do_split(const float4* src, ushort_t* dst, int i, int logK)
{
    float4 v = src[i];
    const int K = 1 << logK;
    const int e0 = i * 4;
    const int r = e0 >> logK, k = e0 & (K - 1);
    ushort_t* row = dst + (size_t)r * 2 * K;
    ushort4 h, l;
    h.x = f2bf(v.x); l.x = f2bf(v.x - bf2f(h.x));
    h.y = f2bf(v.y); l.y = f2bf(v.y - bf2f(h.y));
    h.z = f2bf(v.z); l.z = f2bf(v.z - bf2f(h.z));
    h.w = f2bf(v.w); l.w = f2bf(v.w - bf2f(h.w));
    *reinterpret_cast<ushort4*>(row + k) = h;
    *reinterpret_cast<ushort4*>(row + K + k) = l;
}

// ---- GEMM core: 128x128 split-K over logical K'=3K, physical [h|l] ----
__device__ __attribute__((always_inline)) inline void gemm_body(
    const ushort_t* __restrict__ A, const ushort_t* __restrict__ W,
    float* __restrict__ P, int M, int N, int K, int Kc, int nx, int ny,
    int lin, int nwg, ushort_t* As, ushort_t* Ws)
{
    const int swzb = (lin & 7) * (nwg >> 3) + (lin >> 3);
    const int nxy = nx * ny;
    const int bz  = swzb / nxy;
    const int rem = swzb - bz * nxy;
    const int by  = rem / nx;
    const int bx  = rem - by * nx;

    const int tid  = threadIdx.x;
    const int lane = tid & 63;
    const int wid  = tid >> 6;
    const int row0 = by * 128;
    const int col0 = bx * 128;
    const int k0   = bz * Kc;          // logical k in [0, 3K)
    const int st   = 2 * K;            // physical row stride
    const int aoff = (k0 < K) ? k0 : (k0 - K);           // A logical [h,h,l]
    const int woff = (k0 < 2 * K) ? k0 : (k0 - 2 * K);   // W logical [h,l,h]

    const int srow = wid * 32 + (lane >> 3);
    const int scol = (((lane & 7) ^ ((lane >> 3) & 7))) * 8;
    const ushort_t* Ag = A + (size_t)(row0 + srow) * st + aoff + scol;
    const ushort_t* Wg = W + (size_t)(col0 + srow) * st + woff + scol;

    const int wr = wid >> 1, wc = wid & 1;
    const int l15 = lane & 15;
    const int kh  = lane >> 4;
    const int swz8 = l15 & 7;
    const int ch0 = ((kh + 0) ^ swz8) * 8;
    const int ch1 = ((kh + 4) ^ swz8) * 8;
    int aRow[4], bRow[4];
#pragma unroll
    for (int m = 0; m < 4; ++m) aRow[m] = (wr * 64 + m * 16 + l15) * 64;
#pragma unroll
    for (int n = 0; n < 4; ++n) bRow[n] = (wc * 64 + n * 16 + l15) * 64;

    f32x4 acc[4][4] = {};
    const int NIT = Kc / 64;

    for (int it = 0; it < NIT; ++it) {
        const int kk = it * 64;
#pragma unroll
        for (int i = 0; i < 4; ++i) {
            gload16(Ag + (size_t)(i * 8) * st + kk, &As[(wid * 32 + i * 8) * 64]);
            gload16(Wg + (size_t)(i * 8) * st + kk, &Ws[(wid * 32 + i * 8) * 64]);
        }
        __syncthreads();
#pragma unroll
        for (int ks = 0; ks < 2; ++ks) {
            const int ch = ks ? ch1 : ch0;
            bf16x8 af[4], bf[4];
#pragma unroll
            for (int m = 0; m < 4; ++m)
                af[m] = *reinterpret_cast<const bf16x8*>(&As[aRow[m] + ch]);
#pragma unroll
            for (int n = 0; n < 4; ++n)
                bf[n] = *reinterpret_cast<const bf16x8*>(&Ws[bRow[n] + ch]);
#pragma unroll
            for (int m = 0; m < 4; ++m)
#pragma unroll
                for (int n = 0; n < 4; ++n)
                    acc[m][n] = __builtin_amdgcn_mfma_f32_16x16x32_bf16(
                        af[m], bf[n], acc[m][n], 0, 0, 0);
        }
        __syncthreads();
    }

    float* Pp = P + ((size_t)bz * M + row0) * N + col0;
#pragma unroll
    for (int n = 0; n < 4; ++n) {
        const int col = wc * 64 + n * 16 + l15;
#pragma unroll
        for (int m = 0; m < 4; ++m) {
            const int rb = wr * 64 + m * 16 + kh * 4;
#pragma unroll
            for (int i = 0; i < 4; ++i)
                Pp[(size_t)(rb + i) * N + col] = acc[m][n][i];
        }
    }
}

// plain split-K GEMM kernel (layers 1 and 2)
__global__ __launch_bounds__(256) void gemm_splitk(
    const ushort_t* __restrict__ A, const ushort_t* __restrict__ W,
    float* __restrict__ P, int M, int N, int K, int Kc, int nx, int ny)
{
    __shared__ ushort_t As[128 * 64];
    __shared__ ushort_t Ws[128 * 64];
    gemm_body(A, W, P, M, N, K, Kc, nx, ny, blockIdx.x, gridDim.x, As, Ws);
}

// GEMM0 (384 blocks) + W1/W2 split-conversion (6144 blocks) in ONE dispatch.
__global__ __launch_bounds__(256) void gemm0_cvt12(
    const ushort_t* __restrict__ xb, const ushort_t* __restrict__ Wb0,
    float* __restrict__ P,
    const float4* __restrict__ W1, const float4* __restrict__ W2,
    ushort_t* __restrict__ Wb1, ushort_t* __restrict__ Wb2)
{
    __shared__ ushort_t As[128 * 64];
    __shared__ ushort_t Ws[128 * 64];
    const int b = blockIdx.x;
    if (b < 384) {
        gemm_body(xb, Wb0, P, 256, 2048, 1024, 256, 16, 2, b, 384, As, Ws);
    } else if (b < 384 + 4096) {
        do_split(W1, Wb1, (b - 384) * 256 + threadIdx.x, 11);
    } else {
        do_split(W2, Wb2, (b - 4480) * 256 + threadIdx.x, 11);
    }
}

// ---------------- x + W0 split-conversions ----------------
__global__ __launch_bounds__(256) void cvt_xw0(
    const float4* __restrict__ x, const float4* __restrict__ W0,
    ushort_t* __restrict__ xb, ushort_t* __restrict__ Wb0)
{
    const int b = blockIdx.x, tid = threadIdx.x;
    if (b < 256) do_split(x,  xb,  b * 256 + tid, 10);
    else         do_split(W0, Wb0, (b - 256) * 256 + tid, 10);
}

// ---------------- helpers ----------------
__device__ inline int flag4(float4 v, int e0, int* loc, int lc)
{
    float vv[4] = {v.x, v.y, v.z, v.w};
#pragma unroll
    for (int c = 0; c < 4; ++c)
        if ((fabsf(vv[c] - 1.0f) < SDELTA) || (fabsf(vv[c] - 0.1f) < SDELTA))
            loc[lc++] = e0 + c;
    return lc;
}

__device__ inline void wsplit2(ushort_t* row, int k, float4 v)   // [h|l], width 4096
{
    ushort4 h, l;
    h.x = f2bf(v.x); l.x = f2bf(v.x - bf2f(h.x));
    h.y = f2bf(v.y); l.y = f2bf(v.y - bf2f(h.y));
    h.z = f2bf(v.z); l.z = f2bf(v.z - bf2f(h.z));
    h.w = f2bf(v.w); l.w = f2bf(v.w - bf2f(h.w));
    *reinterpret_cast<ushort4*>(row + k) = h;
    *reinterpret_cast<ushort4*>(row + 2048 + k) = l;
}

__device__ inline void patch2(ushort_t* row, int c, float v)
{
    ushort_t h = f2bf(v);
    ushort_t l = f2bf(v - bf2f(h));
    row[c] = h; row[2048 + c] = l;
}

__device__ inline float4 lifstep(float4 cur, float4 gate)
{
    float4 o;
    o.x = cur.x + ((gate.x > 1.0f) ? 0.9f : 0.0f);
    o.y = cur.y + ((gate.y > 1.0f) ? 0.9f : 0.0f);
    o.z = cur.z + ((gate.z > 1.0f) ? 0.9f : 0.0f);
    o.w = cur.w + ((gate.w > 1.0f) ? 0.9f : 0.0f);
    return o;
}

__device__ inline double wred(double p)
{
#pragma unroll
    for (int off = 32; off; off >>= 1) p += __shfl_down(p, off);
    return __shfl(p, 0);
}

// ---- layer 0: reduce + bias + C0 + A1 [h|l] + IN-BLOCK f64 fixup ----
__global__ __launch_bounds__(256) void fused0(
    const float4* __restrict__ P, const float* __restrict__ bias,
    float* __restrict__ C0f, ushort_t* __restrict__ A1b,
    const float* __restrict__ X, const float* __restrict__ W0,
    const float* __restrict__ b0f)
{
    __shared__ int flist[1024];
    __shared__ int fcnt;
    if (threadIdx.x == 0) fcnt = 0;
    __syncthreads();

    const int i = blockIdx.x * 256 + threadIdx.x;   // < 131072
    float4 s = P[i];
#pragma unroll
    for (int j = 1; j < NS; ++j) {
        float4 t = P[(size_t)j * 131072 + i];
        s.x += t.x; s.y += t.y; s.z += t.z; s.w += t.w;
    }
    const float4 bv = *reinterpret_cast<const float4*>(bias + ((i * 4) & 2047));
    s.x += bv.x; s.y += bv.y; s.z += bv.z; s.w += bv.w;
    reinterpret_cast<float4*>(C0f)[i] = s;
    int loc[4];
    int lc = flag4(s, i * 4, loc, 0);
    for (int j = 0; j < lc; ++j) { int p = atomicAdd(&fcnt, 1); flist[p] = loc[j]; }
    float4 mi = lifstep(s, s);
    const int e0 = i * 4, r = e0 >> 11, k = e0 & 2047;
    wsplit2(A1b + (size_t)r * 4096, k, s);
    wsplit2(A1b + (size_t)(256 + r) * 4096, k, mi);
    __syncthreads();

    const int lane = threadIdx.x & 63;
    const int wid  = threadIdx.x >> 6;
    for (int e = wid; e < fcnt; e += 4) {
        const int idx = flist[e];
        const int rr = idx >> 11, cc = idx & 2047;
        double p = 0.0;
        for (int kk = lane * 4; kk < 1024; kk += 256) {
            float4 a4 = ld4(X + (size_t)rr * 1024 + kk);
            float4 w4 = ld4(W0 + (size_t)cc * 1024 + kk);
            p = fma((double)a4.x, (double)w4.x, p);
            p = fma((double)a4.y, (double)w4.y, p);
            p = fma((double)a4.z, (double)w4.z, p);
            p = fma((double)a4.w, (double)w4.w, p);
        }
        const double tot = wred(p);
        if (lane == 0) {
            float c = (float)(tot + (double)b0f[cc]);
            C0f[idx] = c;
            float mi2 = c + ((c > 1.0f) ? 0.9f : 0.0f);
            patch2(A1b + (size_t)rr * 4096, cc, c);
            patch2(A1b + (size_t)(256 + rr) * 4096, cc, mi2);
        }
    }
}

// ---- layer 1: reduce both halves + C1 + A2 [h|l] + IN-BLOCK f64 fixup ----
__global__ __launch_bounds__(256) void fused1(
    const float4* __restrict__ P, const float* __restrict__ bias,
    float* __restrict__ C1f, ushort_t* __restrict__ A2b,
    const float* __restrict__ C0, const float* __restrict__ W1)
{
    __shared__ int flist[2048];
    __shared__ int fcnt;
    if (threadIdx.x == 0) fcnt = 0;
    __syncthreads();

    const int i = blockIdx.x * 256 + threadIdx.x;   // < 131072
    float4* C1 = reinterpret_cast<float4*>(C1f);
    float4 c0 = P[i];
    float4 ci = P[131072 + i];
#pragma unroll
    for (int j = 1; j < NS; ++j) {
        float4 t0 = P[(size_t)j * 262144 + i];
        float4 t1 = P[(size_t)j * 262144 + 131072 + i];
        c0.x += t0.x; c0.y += t0.y; c0.z += t0.z; c0.w += t0.w;
        ci.x += t1.x; ci.y += t1.y; ci.z += t1.z; ci.w += t1.w;
    }
    const float4 bv = *reinterpret_cast<const float4*>(bias + ((i * 4) & 2047));
    c0.x += bv.x; c0.y += bv.y; c0.z += bv.z; c0.w += bv.w;
    ci.x += bv.x; ci.y += bv.y; ci.z += bv.z; ci.w += bv.w;
    C1[i] = c0;
    C1[131072 + i] = ci;
    int loc[8];
    int lc = flag4(c0, i * 4, loc, 0);
    lc = flag4(ci, (131072 + i) * 4, loc, lc);
    for (int j = 0; j < lc; ++j) { int p = atomicAdd(&fcnt, 1); flist[p] = loc[j]; }
    float4 m1 = lifstep(ci, c0);
    float4 m2 = lifstep(ci, m1);
    const int e0 = i * 4, r = e0 >> 11, k = e0 & 2047;
    wsplit2(A2b + (size_t)r * 4096, k, c0);
    wsplit2(A2b + (size_t)(256 + r) * 4096, k, m1);
    wsplit2(A2b + (size_t)(512 + r) * 4096, k, m2);
    __syncthreads();

    const int lane = threadIdx.x & 63;
    const int wid  = threadIdx.x >> 6;
    for (int e = wid; e < fcnt; e += 4) {
        const int idx = flist[e];
        const int cc = idx & 2047;
        const int rp = (idx >> 11) & 255;
        double p0 = 0.0, p1 = 0.0;
        for (int kk = lane * 4; kk < 2048; kk += 256) {
            float4 a4 = ld4(C0 + (size_t)rp * 2048 + kk);
            float4 w4 = ld4(W1 + (size_t)cc * 2048 + kk);
            float4 b4 = lifstep(a4, a4);
            p0 = fma((double)a4.x, (double)w4.x, p0);
            p0 = fma((double)a4.y, (double)w4.y, p0);
            p0 = fma((double)a4.z, (double)w4.z, p0);
            p0 = fma((double)a4.w, (double)w4.w, p0);
            p1 = fma((double)b4.x, (double)w4.x, p1);
            p1 = fma((double)b4.y, (double)w4.y, p1);
            p1 = fma((double)b4.z, (double)w4.z, p1);
            p1 = fma((double)b4.w, (double)w4.w, p1);
        }
        const double t0 = wred(p0);
        const double t1 = wred(p1);
        if (lane == 0) {
            float fc0 = (float)(t0 + (double)bias[cc]);
            float fci = (float)(t1 + (double)bias[cc]);
            C1f[(size_t)rp * 2048 + cc] = fc0;
            C1f[(size_t)(256 + rp) * 2048 + cc] = fci;
            float m1s = fci + ((fc0 > 1.0f) ? 0.9f : 0.0f);
            float m2s = fci + ((m1s > 1.0f) ? 0.9f : 0.0f);
            patch2(A2b + (size_t)rp * 4096, cc, fc0);
            patch2(A2b + (size_t)(256 + rp) * 4096, cc, m1s);
            patch2(A2b + (size_t)(512 + rp) * 4096, cc, m2s);
        }
    }
}

// ---- layer 2 + broadcast t=0..79: thread i owns all 3 variants; reduce
// S=NS2 + bias + scan + in-block f64 fixup + LIF chain + 80 timestep stores.
// P lives in out's t>=80 tail -> t<=79 stores never race with partial reads.
__global__ __launch_bounds__(256) void fused2_bcast(
    const float4* __restrict__ P, const float* __restrict__ bias,
    float* __restrict__ C2f, const float* __restrict__ C1,
    const float* __restrict__ W2, float4* __restrict__ out)
{
    __shared__ int flist[3072];
    __shared__ int fcnt;
    if (threadIdx.x == 0) fcnt = 0;
    __syncthreads();

    const int i = blockIdx.x * 256 + threadIdx.x;   // < 65536
    float4* C2 = reinterpret_cast<float4*>(C2f);
    const float4 bv = *reinterpret_cast<const float4*>(bias + ((i * 4) & 1023));
#pragma unroll
    for (int v = 0; v < 3; ++v) {
        float4 s = P[(size_t)v * 65536 + i];
#pragma unroll
        for (int j = 1; j < NS2; ++j) {
            float4 t = P[(size_t)j * 196608 + (size_t)v * 65536 + i];
            s.x += t.x; s.y += t.y; s.z += t.z; s.w += t.w;
        }
        s.x += bv.x; s.y += bv.y; s.z += bv.z; s.w += bv.w;
        C2[(size_t)v * 65536 + i] = s;
        int loc[4];
        int lc = flag4(s, (v * 65536 + i) * 4, loc, 0);
        for (int j = 0; j < lc; ++j) { int p = atomicAdd(&fcnt, 1); flist[p] = loc[j]; }
    }
    __syncthreads();

    const int lane = threadIdx.x & 63;
    const int wid  = threadIdx.x >> 6;
    for (int e = wid; e < fcnt; e += 4) {
        const int idx = flist[e];
        const int cc = idx & 1023;
        const int rp = (idx >> 10) & 255;
        double pA = 0.0, pB = 0.0, pC = 0.0;
        for (int kk = lane * 4; kk < 2048; kk += 256) {
            float4 c04 = ld4(C1 + (size_t)rp * 2048 + kk);
            float4 ci4 = ld4(C1 + (size_t)(256 + rp) * 2048 + kk);
            float4 w4  = ld4(W2 + (size_t)cc * 2048 + kk);
            float4 m14 = lifstep(ci4, c04);
            float4 m24 = lifstep(ci4, m14);
            pA = fma((double)c04.x, (double)w4.x, pA);
            pA = fma((double)c04.y, (double)w4.y, pA);
            pA = fma((double)c04.z, (double)w4.z, pA);
            pA = fma((double)c04.w, (double)w4.w, pA);
            pB = fma((double)m14.x, (double)w4.x, pB);
            pB = fma((double)m14.y, (double)w4.y, pB);
            pB = fma((double)m14.z, (double)w4.z, pB);
            pB = fma((double)m14.w, (double)w4.w, pB);
            pC = fma((double)m24.x, (double)w4.x, pC);
            pC = fma((double)m24.y, (double)w4.y, pC);
            pC = fma((double)m24.z, (double)w4.z, pC);
            pC = fma((double)m24.w, (double)w4.w, pC);
        }
        const double tA = wred(pA);
        const double tB = wred(pB);
        const double tC = wred(pC);
        if (lane == 0) {
            C2f[(size_t)rp * 1024 + cc]         = (float)(tA + (double)bias[cc]);
            C2f[(size_t)(256 + rp) * 1024 + cc] = (float)(tB + (double)bias[cc]);
            C2f[(size_t)(512 + rp) * 1024 + cc] = (float)(tC + (double)bias[cc]);
        }
    }
    __syncthreads();

    // re-read finalized C2 (block-local fixups complete) and write t = 0..79
    float4 c0 = C2[i];
    float4 c1 = C2[65536 + i];
    float4 ci = C2[131072 + i];
    float4 m0 = c0;
    float4 m1 = lifstep(c1, m0);
    float4 m2 = lifstep(ci, m1);
    float4 m3 = lifstep(ci, m2);
    out[i] = m0;
    out[65536 + i] = m1;
    out[131072 + i] = m2;
    for (int t = 3; t < 80; ++t)
        out[(size_t)t * 65536 + i] = m3;
}

// ---- broadcast tail t = 80..99 (after fused2_bcast; partials now dead) ----
__global__ __launch_bounds__(256) void tail_bcast(const float4* __restrict__ c2,
                                                  float4* __restrict__ out)
{
    const int i = blockIdx.x * 256 + threadIdx.x;   // < 65536
    float4 c0 = c2[i], c1 = c2[65536 + i], ci = c2[131072 + i];
    float4 m1 = lifstep(c1, c0);
    float4 m2 = lifstep(ci, m1);
    float4 m3 = lifstep(ci, m2);
    const int t0 = 80 + blockIdx.y * 4;
#pragma unroll
    for (int j = 0; j < 4; ++j)
        out[(size_t)(t0 + j) * 65536 + i] = m3;
}

extern "C" void kernel_launch(void* const* d_in, const int* in_sizes, int n_in,
                              void* d_out, int out_size, void* d_ws, size_t ws_size,
                              hipStream_t stream)
{
    const float* x  = (const float*)d_in[0];  // [256,1024]
    const float* W0 = (const float*)d_in[1];  // [2048,1024]
    const float* b0 = (const float*)d_in[2];
    const float* W1 = (const float*)d_in[3];  // [2048,2048]
    const float* b1 = (const float*)d_in[4];
    const float* W2 = (const float*)d_in[5];  // [1024,2048]
    const float* b2 = (const float*)d_in[6];
    float* out = (float*)d_out;
    float* ws  = (float*)d_ws;

    // ws (floats): C0 0.5M | C1 1M | C2 0.75M
    float* C0 = ws;
    float* C1 = ws + 524288;
    float* C2 = ws + 1572864;

    // d_out scratch (overwritten by the t<=79 broadcast + tail), float offsets:
    ushort_t* Wb0 = (ushort_t*)(out);               // [2048,2048] bf16 = 2M floats
    ushort_t* Wb1 = (ushort_t*)(out + 2097152);     // [2048,4096] bf16 = 4M floats
    ushort_t* Wb2 = (ushort_t*)(out + 6291456);     // [1024,4096] bf16 = 2M floats
    ushort_t* xb  = (ushort_t*)(out + 8388608);     // [256,2048]  bf16 = 256K floats
    ushort_t* A1b = (ushort_t*)(out + 8650752);     // [512,4096]  bf16 = 1M floats
    ushort_t* A2b = (ushort_t*)(out + 9699328);     // [768,4096]  bf16 = 1.5M floats
    float* Pbuf   = out + 11272192;                 // GEMM0/1 partials (<=12.6M)
    float* Pbuf2  = out + 20971520;                 // GEMM2 partials: t>=80 tail,
                                                    // 6x768x1024=4.72M <= 5.24M cap

    dim3 blk(256);

    // 1: x + W0 conversions (GEMM0's inputs only)
    cvt_xw0<<<dim3(2304), blk, 0, stream>>>((const float4*)x, (const float4*)W0,
                                            xb, Wb0);

    // 2: GEMM0 (384 blocks, K'=3072 Kc=256 S=12) + W1/W2 conversion overlap
    gemm0_cvt12<<<dim3(6528), blk, 0, stream>>>(xb, Wb0, Pbuf,
                                                (const float4*)W1, (const float4*)W2,
                                                Wb1, Wb2);
    // 3: layer-0 epilogue + in-block fixup
    fused0<<<dim3(512), blk, 0, stream>>>((const float4*)Pbuf, b0, C0,
                                          A1b, x, W0, b0);

    // 4: GEMM1. K'=6144, Kc=512, S=12 -> 768 blocks (3/CU)
    gemm_splitk<<<dim3(768), blk, 0, stream>>>(A1b, Wb1, Pbuf, 512, 2048, 2048, 512, 16, 4);
    // 5: layer-1 epilogue + in-block fixup
    fused1<<<dim3(512), blk, 0, stream>>>((const float4*)Pbuf, b1, C1,
                                          A2b, C0, W1);

    // 6: GEMM2. K'=6144, Kc=1024, S=6 -> 288 blocks; partials in t>=80 tail
    gemm_splitk<<<dim3(288), blk, 0, stream>>>(A2b, Wb2, Pbuf2, 768, 1024, 2048, 1024, 8, 6);
    // 7: layer-2 epilogue + fixup + broadcast t=0..79 (race-free vs Pbuf2)
    fused2_bcast<<<dim3(256), blk, 0, stream>>>((const float4*)Pbuf2, b2, C2, C1, W2,
                                                (float4*)out);
    // 8: broadcast tail t=80..99 (overwrites Pbuf2)
    tail_bcast<<<dim3(256, 5), blk, 0, stream>>>((const float4*)C2, (float4*)out);
}